// Round 1
// baseline (4870.053 us; speedup 1.0000x reference)
//
#include <hip/hip_runtime.h>
#include <math.h>

// Problem constants
constexpr int B_ = 64;
constexpr int D_ = 12288;
constexpr int N_ = 32;    // latent dim
constexpr int H_ = 2048;

// scalar slots in scal[] (each B_ wide)
#define SC_SP  0
#define SC_SV  1
#define SC_SP2 2
#define SC_SV2 3
#define SC_LD  4
#define SC_TI  5
#define SC_ZN  6
#define SC_DSQ 7

// ---------------------------------------------------------------------------
// Generic M=64 GEMM: C(64 x Nn) = A(64 x K) @ op(B) (+ epilogue)
// TRANS_B=0: B is K x Nn (ldb = Nn stride given);  TRANS_B=1: B is Nn x ldb with C[r][n]=sum_k A[r,k]*B[n,k]
// EPI: 0 = relu(acc + bias), 1 = X - (acc + bias)  (delta), 2 = raw acc
// ---------------------------------------------------------------------------
template <int TRANS_B, int EPI>
__global__ __launch_bounds__(256) void gemm64_kernel(
    const float* __restrict__ A, const float* __restrict__ Bm,
    const float* __restrict__ bias, const float* __restrict__ X,
    float* __restrict__ C, int K, int Nn, int ldb)
{
    const int n0 = blockIdx.x * 64;
    __shared__ float As[16][65];
    __shared__ float Bs[16][65];
    const int tid = threadIdx.x;
    const int tx = tid & 15, ty = tid >> 4;
    const int c0 = tx * 4, r0 = ty * 4;
    float acc[4][4] = {};

    for (int k0 = 0; k0 < K; k0 += 16) {
#pragma unroll
        for (int i = 0; i < 4; i++) {
            int idx = tid + i * 256;
            int kk = idx & 15, row = idx >> 4;
            As[kk][row] = A[(size_t)row * K + k0 + kk];
        }
#pragma unroll
        for (int i = 0; i < 4; i++) {
            int idx = tid + i * 256;
            if (TRANS_B) {
                int kk = idx & 15, nn = idx >> 4;
                Bs[kk][nn] = Bm[(size_t)(n0 + nn) * ldb + k0 + kk];
            } else {
                int nn = idx & 63, kk = idx >> 6;
                Bs[kk][nn] = Bm[(size_t)(k0 + kk) * ldb + n0 + nn];
            }
        }
        __syncthreads();
#pragma unroll
        for (int kk = 0; kk < 16; kk++) {
            float a[4], b[4];
#pragma unroll
            for (int i = 0; i < 4; i++) a[i] = As[kk][r0 + i];
#pragma unroll
            for (int j = 0; j < 4; j++) b[j] = Bs[kk][c0 + j];
#pragma unroll
            for (int i = 0; i < 4; i++)
#pragma unroll
                for (int j = 0; j < 4; j++) acc[i][j] += a[i] * b[j];
        }
        __syncthreads();
    }
#pragma unroll
    for (int i = 0; i < 4; i++) {
        int row = r0 + i;
#pragma unroll
        for (int j = 0; j < 4; j++) {
            int col = n0 + c0 + j;
            float v = acc[i][j];
            if (EPI == 0) {
                v = v + bias[col];
                v = v > 0.f ? v : 0.f;
            } else if (EPI == 1) {
                v = X[(size_t)row * Nn + col] - (v + bias[col]);
            }
            C[(size_t)row * Nn + col] = v;
        }
    }
}

// ---------------------------------------------------------------------------
// S = W2 @ W2^T   (H x H, K = D).  Symmetric: only blocks j0 >= i0 computed,
// result mirrored on store.
// ---------------------------------------------------------------------------
__global__ __launch_bounds__(256) void gemm_S_kernel(
    const float* __restrict__ W2, float* __restrict__ S)
{
    if (blockIdx.y > blockIdx.x) return;  // upper triangle only (j0 >= i0)
    const int i0 = blockIdx.y * 128, j0 = blockIdx.x * 128;
    __shared__ float As[16][136];
    __shared__ float Bs[16][136];
    const int tid = threadIdx.x;
    const int tx = tid & 15, ty = tid >> 4;
    const int cr = tx * 8, rr = ty * 8;
    float acc[8][8] = {};

    for (int k0 = 0; k0 < D_; k0 += 16) {
#pragma unroll
        for (int i = 0; i < 8; i++) {
            int idx = tid + i * 256;
            int kk = idx & 15, row = idx >> 4;
            As[kk][row] = W2[(size_t)(i0 + row) * D_ + k0 + kk];
            Bs[kk][row] = W2[(size_t)(j0 + row) * D_ + k0 + kk];
        }
        __syncthreads();
#pragma unroll
        for (int kk = 0; kk < 16; kk++) {
            float a[8], b[8];
#pragma unroll
            for (int i = 0; i < 8; i++) a[i] = As[kk][rr + i];
#pragma unroll
            for (int j = 0; j < 8; j++) b[j] = Bs[kk][cr + j];
#pragma unroll
            for (int i = 0; i < 8; i++)
#pragma unroll
                for (int j = 0; j < 8; j++) acc[i][j] += a[i] * b[j];
        }
        __syncthreads();
    }
#pragma unroll
    for (int i = 0; i < 8; i++)
#pragma unroll
        for (int j = 0; j < 8; j++) {
            float v = acc[i][j];
            S[(size_t)(i0 + rr + i) * H_ + (j0 + cr + j)] = v;
            S[(size_t)(j0 + cr + j) * H_ + (i0 + rr + i)] = v;
        }
}

// ---------------------------------------------------------------------------
// T = W1m @ S   where W1m[(b*32+n), k] = W1[n,k] * mask[b,k]
// M = B*N = 2048, K = H, N = H
// ---------------------------------------------------------------------------
__global__ __launch_bounds__(256) void gemm_T_kernel(
    const float* __restrict__ W1, const float* __restrict__ mask,
    const float* __restrict__ S, float* __restrict__ T)
{
    const int m0 = blockIdx.y * 128, j0 = blockIdx.x * 128;
    __shared__ float As[16][136];
    __shared__ float Bs[16][136];
    const int tid = threadIdx.x;
    const int tx = tid & 15, ty = tid >> 4;
    const int cr = tx * 8, rr = ty * 8;
    float acc[8][8] = {};

    for (int k0 = 0; k0 < H_; k0 += 16) {
#pragma unroll
        for (int i = 0; i < 8; i++) {
            int idx = tid + i * 256;
            int kk = idx & 15, row = idx >> 4;
            int m = m0 + row;
            As[kk][row] = W1[(size_t)(m & 31) * H_ + k0 + kk] *
                          mask[(size_t)(m >> 5) * H_ + k0 + kk];
        }
#pragma unroll
        for (int i = 0; i < 8; i++) {
            int idx = tid + i * 256;
            int nn = idx & 127, kk = idx >> 7;
            Bs[kk][nn] = S[(size_t)(k0 + kk) * H_ + j0 + nn];
        }
        __syncthreads();
#pragma unroll
        for (int kk = 0; kk < 16; kk++) {
            float a[8], b[8];
#pragma unroll
            for (int i = 0; i < 8; i++) a[i] = As[kk][rr + i];
#pragma unroll
            for (int j = 0; j < 8; j++) b[j] = Bs[kk][cr + j];
#pragma unroll
            for (int i = 0; i < 8; i++)
#pragma unroll
                for (int j = 0; j < 8; j++) acc[i][j] += a[i] * b[j];
        }
        __syncthreads();
    }
#pragma unroll
    for (int i = 0; i < 8; i++)
#pragma unroll
        for (int j = 0; j < 8; j++)
            T[(size_t)(m0 + rr + i) * H_ + (j0 + cr + j)] = acc[i][j];
}

// ---------------------------------------------------------------------------
// G[b][n][m] = sum_j T[b*32+n][j] * W1[m][j]*mask[b][j]   (one block per batch)
// ---------------------------------------------------------------------------
__global__ __launch_bounds__(256) void gbatched_kernel(
    const float* __restrict__ T, const float* __restrict__ W1,
    const float* __restrict__ mask, float* __restrict__ G)
{
    const int b = blockIdx.x, tid = threadIdx.x;
    __shared__ float Ts[N_][129];
    __shared__ float Ws[N_][129];
    const int n = tid >> 3;
    const int mg = (tid & 7) * 4;
    float acc[4] = {};
    for (int k0 = 0; k0 < H_; k0 += 128) {
#pragma unroll
        for (int i = 0; i < 16; i++) {
            int idx = tid + i * 256;
            int kk = idx & 127, row = idx >> 7;
            Ts[row][kk] = T[((size_t)b * N_ + row) * H_ + k0 + kk];
            Ws[row][kk] = W1[(size_t)row * H_ + k0 + kk] * mask[(size_t)b * H_ + k0 + kk];
        }
        __syncthreads();
        for (int kk = 0; kk < 128; kk++) {
            float tv = Ts[n][kk];
#pragma unroll
            for (int j = 0; j < 4; j++) acc[j] += tv * Ws[mg + j][kk];
        }
        __syncthreads();
    }
#pragma unroll
    for (int j = 0; j < 4; j++)
        G[((size_t)b * N_ + n) * N_ + mg + j] = acc[j];
}

// ---------------------------------------------------------------------------
// Per-batch: z_star = h1 @ enc_W2 + b2;  sp, sv, ||z||^2;  mask1 from dec pre1
// ---------------------------------------------------------------------------
__global__ __launch_bounds__(256) void zstar_kernel(
    const float* __restrict__ h1, const float* __restrict__ encW2,
    const float* __restrict__ encb2, const float* __restrict__ decW1,
    const float* __restrict__ decb1, const float* __restrict__ sigW,
    const float* __restrict__ sigb, float* __restrict__ z_star,
    float* __restrict__ mask1, float* __restrict__ scal)
{
    const int b = blockIdx.x, tid = threadIdx.x;
    __shared__ float hs[H_];
    __shared__ float zs[N_];
    __shared__ float red[256];
    for (int j = tid; j < H_; j += 256) hs[j] = h1[(size_t)b * H_ + j];
    __syncthreads();
    const int n = tid >> 3, lane = tid & 7;
    float p = 0.f;
    for (int j = lane; j < H_; j += 8) p += hs[j] * encW2[(size_t)j * N_ + n];
    red[tid] = p;
    __syncthreads();
    if (lane == 0) {
        float s = 0.f;
#pragma unroll
        for (int l = 0; l < 8; l++) s += red[n * 8 + l];
        zs[n] = s + encb2[n];
    }
    __syncthreads();
    if (tid == 0) {
        float zn = 0.f, a0 = sigb[0], a1 = sigb[1];
        for (int k = 0; k < N_; k++) {
            zn += zs[k] * zs[k];
            a0 += zs[k] * sigW[k * 2 + 0];
            a1 += zs[k] * sigW[k * 2 + 1];
        }
        scal[SC_SP * B_ + b] = expf(a0);
        scal[SC_SV * B_ + b] = expf(a1);
        scal[SC_ZN * B_ + b] = zn;
    }
    if (tid < N_) z_star[(size_t)b * N_ + tid] = zs[tid];
    for (int j = tid; j < H_; j += 256) {
        float pre = decb1[j];
        for (int k = 0; k < N_; k++) pre += zs[k] * decW1[(size_t)k * H_ + j];
        mask1[(size_t)b * H_ + j] = pre > 0.f ? 1.f : 0.f;
    }
}

// ---------------------------------------------------------------------------
// Per-batch: Prec = G/sp^2 + sig_term + I; Cholesky; logdet; trace(Prec^-1);
// dz = L^-T eps; z_s; sp2/sv2; h2 = relu(pre2), mask2.
// ---------------------------------------------------------------------------
__global__ __launch_bounds__(64) void chol_kernel(
    const float* __restrict__ G, const float* __restrict__ sigW,
    const float* __restrict__ sigb, const float* __restrict__ eps,
    const float* __restrict__ z_star, const float* __restrict__ decW1,
    const float* __restrict__ decb1, float* __restrict__ z_s,
    float* __restrict__ h2, float* __restrict__ mask2, float* __restrict__ scal)
{
    const int b = blockIdx.x, tid = threadIdx.x;
    __shared__ float A[N_][N_ + 1];
    __shared__ float Y[N_][N_ + 1];
    __shared__ float zsh[N_], dz[N_];
    const float sp = scal[SC_SP * B_ + b];
    const float isp2 = 1.f / (sp * sp);
    for (int idx = tid; idx < N_ * N_; idx += 64) {
        int i = idx >> 5, j = idx & 31;
        float st = 0.5f * ((float)N_ * sigW[i * 2] * sigW[j * 2] +
                           (float)(D_ - N_) * sigW[i * 2 + 1] * sigW[j * 2 + 1]);
        A[i][j] = G[((size_t)b * N_ + i) * N_ + j] * isp2 + st + (i == j ? 1.f : 0.f);
    }
    __syncthreads();
    // Cholesky (lower, in place)
    for (int k = 0; k < N_; k++) {
        if (tid == 0) A[k][k] = sqrtf(A[k][k]);
        __syncthreads();
        if (tid > k && tid < N_) A[tid][k] /= A[k][k];
        __syncthreads();
        int w = N_ - 1 - k;
        for (int idx = tid; idx < w * w; idx += 64) {
            int ii = k + 1 + idx / w, jj = k + 1 + idx % w;
            if (jj <= ii) A[ii][jj] -= A[ii][k] * A[jj][k];
        }
        __syncthreads();
    }
    if (tid == 0) {
        float ld = 0.f;
        for (int k = 0; k < N_; k++) ld += logf(A[k][k]);
        scal[SC_LD * B_ + b] = ld;
    }
    // columns of L^-1
    if (tid < N_) {
        int c = tid;
        for (int i = 0; i < N_; i++) {
            float s = (i == c) ? 1.f : 0.f;
            for (int k = c; k < i; k++) s -= A[i][k] * Y[k][c];
            Y[i][c] = (i >= c) ? s / A[i][i] : 0.f;
        }
    }
    __syncthreads();
    float ts = 0.f;
    for (int idx = tid; idx < N_ * N_; idx += 64) {
        float y = Y[idx >> 5][idx & 31];
        ts += y * y;
    }
    for (int off = 32; off > 0; off >>= 1) ts += __shfl_down(ts, off, 64);
    if (tid == 0) scal[SC_TI * B_ + b] = ts;
    // dz = L^-T eps   (back substitution)
    if (tid == 0) {
        for (int i = N_ - 1; i >= 0; i--) {
            float s = eps[(size_t)b * N_ + i];
            for (int k = i + 1; k < N_; k++) s -= A[k][i] * dz[k];
            dz[i] = s / A[i][i];
        }
    }
    __syncthreads();
    if (tid < N_) {
        zsh[tid] = z_star[(size_t)b * N_ + tid] + dz[tid];
        z_s[(size_t)b * N_ + tid] = zsh[tid];
    }
    __syncthreads();
    if (tid == 0) {
        float a0 = sigb[0], a1 = sigb[1];
        for (int k = 0; k < N_; k++) {
            a0 += zsh[k] * sigW[k * 2 + 0];
            a1 += zsh[k] * sigW[k * 2 + 1];
        }
        scal[SC_SP2 * B_ + b] = expf(a0);
        scal[SC_SV2 * B_ + b] = expf(a1);
    }
    for (int j = tid; j < H_; j += 64) {
        float pre = decb1[j];
        for (int k = 0; k < N_; k++) pre += zsh[k] * decW1[(size_t)k * H_ + j];
        h2[(size_t)b * H_ + j] = pre > 0.f ? pre : 0.f;
        mask2[(size_t)b * H_ + j] = pre > 0.f ? 1.f : 0.f;
    }
}

// ---------------------------------------------------------------------------
__global__ __launch_bounds__(256) void dsq_kernel(
    const float* __restrict__ delta, float* __restrict__ scal)
{
    const int b = blockIdx.x, tid = threadIdx.x;
    float s = 0.f;
    for (int j = tid; j < D_; j += 256) {
        float d = delta[(size_t)b * D_ + j];
        s += d * d;
    }
    __shared__ float red[256];
    red[tid] = s;
    __syncthreads();
    for (int off = 128; off > 0; off >>= 1) {
        if (tid < off) red[tid] += red[tid + off];
        __syncthreads();
    }
    if (tid == 0) scal[SC_DSQ * B_ + b] = red[0];
}

// ---------------------------------------------------------------------------
// Per batch: t = W1m2 @ V;  chol(G2); sol = G2^-1 t; d_proj; final output.
// ---------------------------------------------------------------------------
__global__ __launch_bounds__(256) void final_kernel(
    const float* __restrict__ V, const float* __restrict__ W1,
    const float* __restrict__ mask2, const float* __restrict__ G2,
    const float* __restrict__ scal, float* __restrict__ out)
{
    const int b = blockIdx.x, tid = threadIdx.x;
    __shared__ float A[N_][N_ + 1];
    __shared__ float red[256];
    __shared__ float t[N_], y[N_], sol[N_];
    const int n = tid >> 3, lane = tid & 7;
    float p = 0.f;
    for (int j = lane; j < H_; j += 8)
        p += W1[(size_t)n * H_ + j] * mask2[(size_t)b * H_ + j] * V[(size_t)b * H_ + j];
    red[tid] = p;
    for (int idx = tid; idx < N_ * N_; idx += 256)
        A[idx >> 5][idx & 31] = G2[(size_t)b * N_ * N_ + idx];
    __syncthreads();
    if (lane == 0) {
        float s = 0.f;
#pragma unroll
        for (int l = 0; l < 8; l++) s += red[n * 8 + l];
        t[n] = s;
    }
    __syncthreads();
    for (int k = 0; k < N_; k++) {
        if (tid == 0) A[k][k] = sqrtf(A[k][k]);
        __syncthreads();
        if (tid > k && tid < N_) A[tid][k] /= A[k][k];
        __syncthreads();
        int w = N_ - 1 - k;
        for (int idx = tid; idx < w * w; idx += 256) {
            int ii = k + 1 + idx / w, jj = k + 1 + idx % w;
            if (jj <= ii) A[ii][jj] -= A[ii][k] * A[jj][k];
        }
        __syncthreads();
    }
    if (tid == 0) {
        for (int i = 0; i < N_; i++) {
            float s = t[i];
            for (int k = 0; k < i; k++) s -= A[i][k] * y[k];
            y[i] = s / A[i][i];
        }
        for (int i = N_ - 1; i >= 0; i--) {
            float s = y[i];
            for (int k = i + 1; k < N_; k++) s -= A[k][i] * sol[k];
            sol[i] = s / A[i][i];
        }
        float dproj = 0.f;
        for (int i = 0; i < N_; i++) dproj += t[i] * sol[i];
        float sp2 = scal[SC_SP2 * B_ + b], sv2 = scal[SC_SV2 * B_ + b];
        float recon = scal[SC_DSQ * B_ + b] / (2.f * sv2 * sv2) +
                      dproj * (0.5f / (sp2 * sp2) - 0.5f / (sv2 * sv2)) +
                      (float)N_ * logf(sp2) + (float)(D_ - N_) * logf(sv2);
        float res = recon + 0.5f * scal[SC_ZN * B_ + b] + 0.5f * scal[SC_TI * B_ + b] +
                    scal[SC_LD * B_ + b];
        out[b] = res / (float)D_;
    }
}

// ---------------------------------------------------------------------------
extern "C" void kernel_launch(void* const* d_in, const int* in_sizes, int n_in,
                              void* d_out, int out_size, void* d_ws, size_t ws_size,
                              hipStream_t stream)
{
    const float* x     = (const float*)d_in[0];
    const float* eps   = (const float*)d_in[1];
    const float* encW1 = (const float*)d_in[2];
    const float* encb1 = (const float*)d_in[3];
    const float* encW2 = (const float*)d_in[4];
    const float* encb2 = (const float*)d_in[5];
    const float* decW1 = (const float*)d_in[6];
    const float* decb1 = (const float*)d_in[7];
    const float* decW2 = (const float*)d_in[8];
    const float* decb2 = (const float*)d_in[9];
    const float* sigW  = (const float*)d_in[10];
    const float* sigb  = (const float*)d_in[11];
    float* out = (float*)d_out;

    float* ws = (float*)d_ws;
    size_t off = 0;
    auto alloc = [&](size_t nel) { float* p = ws + off; off += nel; return p; };
    float* S     = alloc((size_t)H_ * H_);
    float* T     = alloc((size_t)B_ * N_ * H_);
    float* h1    = alloc((size_t)B_ * H_);
    float* h2    = alloc((size_t)B_ * H_);
    float* mask1 = alloc((size_t)B_ * H_);
    float* mask2 = alloc((size_t)B_ * H_);
    float* delta = alloc((size_t)B_ * D_);
    float* Vb    = alloc((size_t)B_ * H_);
    float* zst   = alloc((size_t)B_ * N_);
    float* zs2   = alloc((size_t)B_ * N_);
    float* G     = alloc((size_t)B_ * N_ * N_);
    float* G2    = alloc((size_t)B_ * N_ * N_);
    float* scal  = alloc(8 * B_);
    (void)ws_size; (void)n_in; (void)in_sizes; (void)out_size;

    // 1. h1 = relu(x @ enc_W1 + b1)
    gemm64_kernel<0, 0><<<H_ / 64, 256, 0, stream>>>(x, encW1, encb1, nullptr, h1, D_, H_, H_);
    // 2. z_star, sp, sv, ||z||^2, mask1
    zstar_kernel<<<B_, 256, 0, stream>>>(h1, encW2, encb2, decW1, decb1, sigW, sigb,
                                         zst, mask1, scal);
    // 3. S = dec_W2 @ dec_W2^T
    gemm_S_kernel<<<dim3(16, 16), 256, 0, stream>>>(decW2, S);
    // 4. T = W1m1 @ S
    gemm_T_kernel<<<dim3(16, 16), 256, 0, stream>>>(decW1, mask1, S, T);
    // 5. G
    gbatched_kernel<<<B_, 256, 0, stream>>>(T, decW1, mask1, G);
    // 6. Cholesky pipeline -> logdet, trinv, z_s, sp2, sv2, h2, mask2
    chol_kernel<<<B_, 64, 0, stream>>>(G, sigW, sigb, eps, zst, decW1, decb1,
                                       zs2, h2, mask2, scal);
    // 7. delta = x - (h2 @ dec_W2 + b2)
    gemm64_kernel<0, 1><<<D_ / 64, 256, 0, stream>>>(h2, decW2, decb2, x, delta, H_, D_, D_);
    // 8. d_sq
    dsq_kernel<<<B_, 256, 0, stream>>>(delta, scal);
    // 9. V = delta @ dec_W2^T
    gemm64_kernel<1, 2><<<H_ / 64, 256, 0, stream>>>(delta, decW2, nullptr, nullptr, Vb, D_, H_, D_);
    // 10. T2 = W1m2 @ S (reuse T)
    gemm_T_kernel<<<dim3(16, 16), 256, 0, stream>>>(decW1, mask2, S, T);
    // 11. G2
    gbatched_kernel<<<B_, 256, 0, stream>>>(T, decW1, mask2, G2);
    // 12. final
    final_kernel<<<B_, 256, 0, stream>>>(Vb, decW1, mask2, G2, scal, out);
}

// Round 2
// 1081.914 us; speedup vs baseline: 4.5013x; 4.5013x over previous
//
#include <hip/hip_runtime.h>
#include <math.h>
#include <stdint.h>

constexpr int B_ = 64;
constexpr int D_ = 12288;
constexpr int N_ = 32;
constexpr int H_ = 2048;

#define SC_SP  0
#define SC_SV  1
#define SC_SP2 2
#define SC_SV2 3
#define SC_LD  4
#define SC_TI  5
#define SC_ZN  6
#define SC_DSQ 7

typedef unsigned short u16;
typedef __bf16 bf16x8 __attribute__((ext_vector_type(8)));
typedef float f32x4 __attribute__((ext_vector_type(4)));
typedef float f4 __attribute__((ext_vector_type(4)));
typedef unsigned int u32x4 __attribute__((ext_vector_type(4)));

__device__ inline u16 f2bf(float f) {
    union { float f; uint32_t u; } v; v.f = f;
    uint32_t u = v.u;
    u += 0x7fffu + ((u >> 16) & 1u);   // round-to-nearest-even
    return (u16)(u >> 16);
}

// ---------------------------------------------------------------------------
// convW2: decW2 (H x D fp32) -> w2b (bf16), and w2b2[h] = sum_d W2[h,d]*b2[d]
// ---------------------------------------------------------------------------
__global__ __launch_bounds__(256) void convW2_kernel(
    const float* __restrict__ W2, const float* __restrict__ b2,
    u16* __restrict__ w2b, float* __restrict__ w2b2)
{
    const int h = blockIdx.x, tid = threadIdx.x;
    const float* src = W2 + (size_t)h * D_;
    u16* dst = w2b + (size_t)h * D_;
    float s = 0.f;
    for (int d = tid * 4; d < D_; d += 1024) {
        f4 v = *reinterpret_cast<const f4*>(&src[d]);
        f4 bv = *reinterpret_cast<const f4*>(&b2[d]);
        uint32_t p0 = (uint32_t)f2bf(v[0]) | ((uint32_t)f2bf(v[1]) << 16);
        uint32_t p1 = (uint32_t)f2bf(v[2]) | ((uint32_t)f2bf(v[3]) << 16);
        *reinterpret_cast<uint32_t*>(&dst[d]) = p0;
        *reinterpret_cast<uint32_t*>(&dst[d + 2]) = p1;
        s += v[0] * bv[0] + v[1] * bv[1] + v[2] * bv[2] + v[3] * bv[3];
    }
    __shared__ float red[256];
    red[tid] = s; __syncthreads();
    for (int off = 128; off > 0; off >>= 1) {
        if (tid < off) red[tid] += red[tid + off];
        __syncthreads();
    }
    if (tid == 0) w2b2[h] = red[0];
}

// ---------------------------------------------------------------------------
// convX: x fp32 -> bf16
// ---------------------------------------------------------------------------
__global__ __launch_bounds__(256) void convX_kernel(
    const float* __restrict__ x, u16* __restrict__ xb)
{
    int i = (blockIdx.x * 256 + threadIdx.x) * 4;
    f4 v = *reinterpret_cast<const f4*>(&x[i]);
    uint32_t p0 = (uint32_t)f2bf(v[0]) | ((uint32_t)f2bf(v[1]) << 16);
    uint32_t p1 = (uint32_t)f2bf(v[2]) | ((uint32_t)f2bf(v[3]) << 16);
    *reinterpret_cast<uint32_t*>(&xb[i]) = p0;
    *reinterpret_cast<uint32_t*>(&xb[i + 2]) = p1;
}

// ---------------------------------------------------------------------------
// mfma128: C(bf16) = A(MxK bf16) * B^T (NxK bf16); 128x128 tile, row stride K.
// SYM=1: A==B symmetric output, compute upper block-triangle, mirror store.
// ---------------------------------------------------------------------------
template <int SYM>
__global__ __launch_bounds__(256) void mfma128_kernel(
    const u16* __restrict__ A, const u16* __restrict__ B,
    u16* __restrict__ C, int K, int Nout)
{
    const int bx = blockIdx.x, by = blockIdx.y;
    if (SYM && by > bx) return;
    const int m0 = by * 128, n0 = bx * 128;
    __shared__ u16 As[128 * 40];
    __shared__ u16 Bs[128 * 40];
    const int tid = threadIdx.x;
    const int w = tid >> 6, lane = tid & 63, quad = lane >> 4, l16 = lane & 15;
    const int moff = (w >> 1) * 64, noff = (w & 1) * 64;
    f32x4 acc[4][4];
#pragma unroll
    for (int i = 0; i < 4; i++)
#pragma unroll
        for (int j = 0; j < 4; j++) acc[i][j] = (f32x4){0.f, 0.f, 0.f, 0.f};

    for (int k0 = 0; k0 < K; k0 += 32) {
#pragma unroll
        for (int it = 0; it < 2; it++) {
            int c = tid + it * 256;
            int row = c >> 2, k8 = (c & 3) * 8;
            *reinterpret_cast<u32x4*>(&As[row * 40 + k8]) =
                *reinterpret_cast<const u32x4*>(&A[(size_t)(m0 + row) * K + k0 + k8]);
            *reinterpret_cast<u32x4*>(&Bs[row * 40 + k8]) =
                *reinterpret_cast<const u32x4*>(&B[(size_t)(n0 + row) * K + k0 + k8]);
        }
        __syncthreads();
        bf16x8 a[4], bb[4];
#pragma unroll
        for (int t = 0; t < 4; t++) {
            a[t]  = *reinterpret_cast<const bf16x8*>(&As[(moff + t * 16 + l16) * 40 + quad * 8]);
            bb[t] = *reinterpret_cast<const bf16x8*>(&Bs[(noff + t * 16 + l16) * 40 + quad * 8]);
        }
#pragma unroll
        for (int mt = 0; mt < 4; mt++)
#pragma unroll
            for (int nt = 0; nt < 4; nt++)
                acc[mt][nt] = __builtin_amdgcn_mfma_f32_16x16x32_bf16(a[mt], bb[nt], acc[mt][nt], 0, 0, 0);
        __syncthreads();
    }
#pragma unroll
    for (int mt = 0; mt < 4; mt++)
#pragma unroll
        for (int nt = 0; nt < 4; nt++) {
            int rbase = m0 + moff + mt * 16 + quad * 4;
            int col = n0 + noff + nt * 16 + l16;
#pragma unroll
            for (int i = 0; i < 4; i++) {
                u16 v = f2bf(acc[mt][nt][i]);
                C[(size_t)(rbase + i) * Nout + col] = v;
                if (SYM) C[(size_t)col * Nout + (rbase + i)] = v;
            }
        }
}

// ---------------------------------------------------------------------------
// skinny64: C(64 x Nn) = A(64 x K bf16) * B^T, split-K over blockIdx.y.
// BMODE 0: B bf16 row-major (N x K).  BMODE 1: B fp32 K-major (transpose+cvt).
// EPI 0: write fp32 partial slab.  EPI 1: V = sum(Pp) - acc - w2b2 (KS must be 1)
// ---------------------------------------------------------------------------
template <int BMODE, int EPI>
__global__ __launch_bounds__(256) void skinny_kernel(
    const u16* __restrict__ A, int lda,
    const void* __restrict__ Bp, int ldb,
    int Kchunk, int Nout,
    float* __restrict__ Cp,
    const float* __restrict__ Pp, const float* __restrict__ w2b2,
    float* __restrict__ V)
{
    const int n0 = blockIdx.x * 64;
    const int kbase = blockIdx.y * Kchunk;
    __shared__ u16 As[64 * 40];
    __shared__ u16 Bs[64 * 40];
    const int tid = threadIdx.x;
    const int w = tid >> 6, lane = tid & 63, quad = lane >> 4, l16 = lane & 15;
    f32x4 acc[4];
#pragma unroll
    for (int t = 0; t < 4; t++) acc[t] = (f32x4){0.f, 0.f, 0.f, 0.f};

    for (int kt = 0; kt < Kchunk; kt += 32) {
        const int k0 = kbase + kt;
        {
            int row = tid >> 2, k8 = (tid & 3) * 8;
            *reinterpret_cast<u32x4*>(&As[row * 40 + k8]) =
                *reinterpret_cast<const u32x4*>(&A[(size_t)row * lda + k0 + k8]);
        }
        if (BMODE == 0) {
            const u16* Bb = (const u16*)Bp;
            int row = tid >> 2, k8 = (tid & 3) * 8;
            *reinterpret_cast<u32x4*>(&Bs[row * 40 + k8]) =
                *reinterpret_cast<const u32x4*>(&Bb[(size_t)(n0 + row) * ldb + k0 + k8]);
        } else {
            const float* Bf = (const float*)Bp;
            int kk = tid >> 4, n4 = (tid & 15) * 4;
            f4 v0 = *reinterpret_cast<const f4*>(&Bf[(size_t)(k0 + kk) * ldb + n0 + n4]);
            f4 v1 = *reinterpret_cast<const f4*>(&Bf[(size_t)(k0 + kk + 16) * ldb + n0 + n4]);
#pragma unroll
            for (int i = 0; i < 4; i++) {
                Bs[(n4 + i) * 40 + kk] = f2bf(v0[i]);
                Bs[(n4 + i) * 40 + kk + 16] = f2bf(v1[i]);
            }
        }
        __syncthreads();
        bf16x8 bb = *reinterpret_cast<const bf16x8*>(&Bs[(w * 16 + l16) * 40 + quad * 8]);
#pragma unroll
        for (int mt = 0; mt < 4; mt++) {
            bf16x8 a = *reinterpret_cast<const bf16x8*>(&As[(mt * 16 + l16) * 40 + quad * 8]);
            acc[mt] = __builtin_amdgcn_mfma_f32_16x16x32_bf16(a, bb, acc[mt], 0, 0, 0);
        }
        __syncthreads();
    }
#pragma unroll
    for (int mt = 0; mt < 4; mt++)
#pragma unroll
        for (int i = 0; i < 4; i++) {
            int row = mt * 16 + quad * 4 + i;
            int col = n0 + w * 16 + l16;
            if (EPI == 0) {
                Cp[(size_t)blockIdx.y * 64 * Nout + (size_t)row * Nout + col] = acc[mt][i];
            } else {
                float ps = 0.f;
#pragma unroll
                for (int s = 0; s < 8; s++) ps += Pp[(size_t)s * 64 * Nout + (size_t)row * Nout + col];
                V[(size_t)row * Nout + col] = ps - acc[mt][i] - w2b2[col];
            }
        }
}

// ---------------------------------------------------------------------------
// gbat: G[b] = T_b (32xH) * wm_b^T (32xH) -> 32x32 fp32. 4 waves = 4 tiles.
// ---------------------------------------------------------------------------
__global__ __launch_bounds__(256) void gbat_kernel(
    const u16* __restrict__ T, const u16* __restrict__ wm, float* __restrict__ G)
{
    const int b = blockIdx.x, tid = threadIdx.x;
    const int w = tid >> 6, lane = tid & 63, quad = lane >> 4, l16 = lane & 15;
    const u16* Ta = T + ((size_t)b * 32 + (w >> 1) * 16 + l16) * H_ + quad * 8;
    const u16* Wb = wm + ((size_t)b * 32 + (w & 1) * 16 + l16) * H_ + quad * 8;
    f32x4 acc = (f32x4){0.f, 0.f, 0.f, 0.f};
    for (int k = 0; k < H_; k += 32) {
        bf16x8 a  = *reinterpret_cast<const bf16x8*>(Ta + k);
        bf16x8 bb = *reinterpret_cast<const bf16x8*>(Wb + k);
        acc = __builtin_amdgcn_mfma_f32_16x16x32_bf16(a, bb, acc, 0, 0, 0);
    }
    const int row = (w >> 1) * 16 + quad * 4, col = (w & 1) * 16 + l16;
#pragma unroll
    for (int i = 0; i < 4; i++)
        G[(size_t)b * 1024 + (size_t)(row + i) * 32 + col] = acc[i];
}

// ---------------------------------------------------------------------------
// zstar: reduce h1 slabs, z = h1 @ encW2 + b2e; sp, sv, ||z||^2
// ---------------------------------------------------------------------------
__global__ __launch_bounds__(256) void zstar_kernel(
    const float* __restrict__ h1p, const float* __restrict__ encb1,
    const float* __restrict__ encW2, const float* __restrict__ encb2,
    const float* __restrict__ sigW, const float* __restrict__ sigb,
    float* __restrict__ zst, float* __restrict__ scal)
{
    const int b = blockIdx.x, tid = threadIdx.x;
    __shared__ float hs[H_];
    __shared__ float red[256];
    __shared__ float zsm[N_];
    for (int j = tid; j < H_; j += 256) {
        float s = encb1[j];
#pragma unroll
        for (int t = 0; t < 8; t++) s += h1p[(size_t)t * (64 * H_) + (size_t)b * H_ + j];
        hs[j] = s > 0.f ? s : 0.f;
    }
    __syncthreads();
    const int n = tid & 31, g = tid >> 5;
    float p = 0.f;
    for (int j = g; j < H_; j += 8) p += hs[j] * encW2[j * 32 + n];
    red[tid] = p;
    __syncthreads();
    if (tid < 32) {
        float s = encb2[tid];
#pragma unroll
        for (int t = 0; t < 8; t++) s += red[t * 32 + tid];
        zsm[tid] = s;
        zst[(size_t)b * N_ + tid] = s;
    }
    __syncthreads();
    if (tid == 0) {
        float zn = 0.f, a0 = sigb[0], a1 = sigb[1];
        for (int k = 0; k < N_; k++) {
            zn += zsm[k] * zsm[k];
            a0 += zsm[k] * sigW[k * 2 + 0];
            a1 += zsm[k] * sigW[k * 2 + 1];
        }
        scal[SC_SP * B_ + b] = expf(a0);
        scal[SC_SV * B_ + b] = expf(a1);
        scal[SC_ZN * B_ + b] = zn;
    }
}

// ---------------------------------------------------------------------------
// build_wm: pre = z@W1dec + b1; mask; wm[(b,n),k] = bf16(W1[n,k]*mask[k]).
// HOUT: also h (fp32+bf16) and mask (fp32) outputs.
// ---------------------------------------------------------------------------
template <int HOUT>
__global__ __launch_bounds__(256) void build_wm_kernel(
    const float* __restrict__ z, const float* __restrict__ W1,
    const float* __restrict__ b1, u16* __restrict__ wm,
    u16* __restrict__ hb, float* __restrict__ hf, float* __restrict__ maskf)
{
    const int b = blockIdx.x, tid = threadIdx.x;
    __shared__ float zs[N_];
    __shared__ float ms[H_];
    if (tid < N_) zs[tid] = z[(size_t)b * N_ + tid];
    __syncthreads();
    for (int j = tid; j < H_; j += 256) {
        float pre = b1[j];
#pragma unroll
        for (int k = 0; k < N_; k++) pre += zs[k] * W1[k * H_ + j];
        float m = pre > 0.f ? 1.f : 0.f;
        ms[j] = m;
        if (HOUT) {
            float h = pre > 0.f ? pre : 0.f;
            hf[(size_t)b * H_ + j] = h;
            hb[(size_t)b * H_ + j] = f2bf(h);
            maskf[(size_t)b * H_ + j] = m;
        }
    }
    __syncthreads();
    for (int n = 0; n < N_; n++)
        for (int j = tid; j < H_; j += 256)
            wm[((size_t)b * N_ + n) * H_ + j] = f2bf(W1[n * H_ + j] * ms[j]);
}

// ---------------------------------------------------------------------------
// chol: Prec = G/sp^2 + sig_term + I; Cholesky; logdet; tr(Prec^-1);
// dz = L^-T eps; z_s; sp2/sv2.
// ---------------------------------------------------------------------------
__global__ __launch_bounds__(64) void chol_kernel(
    const float* __restrict__ G, const float* __restrict__ sigW,
    const float* __restrict__ sigb, const float* __restrict__ eps,
    const float* __restrict__ zst, float* __restrict__ zs2,
    float* __restrict__ scal)
{
    const int b = blockIdx.x, tid = threadIdx.x;
    __shared__ float A[N_][N_ + 1];
    __shared__ float Y[N_][N_ + 1];
    __shared__ float zsh[N_], dz[N_];
    const float sp = scal[SC_SP * B_ + b];
    const float isp2 = 1.f / (sp * sp);
    for (int idx = tid; idx < N_ * N_; idx += 64) {
        int i = idx >> 5, j = idx & 31;
        float st = 0.5f * ((float)N_ * sigW[i * 2] * sigW[j * 2] +
                           (float)(D_ - N_) * sigW[i * 2 + 1] * sigW[j * 2 + 1]);
        A[i][j] = G[((size_t)b * N_ + i) * N_ + j] * isp2 + st + (i == j ? 1.f : 0.f);
    }
    __syncthreads();
    for (int k = 0; k < N_; k++) {
        if (tid == 0) A[k][k] = sqrtf(A[k][k]);
        __syncthreads();
        if (tid > k && tid < N_) A[tid][k] /= A[k][k];
        __syncthreads();
        int w = N_ - 1 - k;
        for (int idx = tid; idx < w * w; idx += 64) {
            int ii = k + 1 + idx / w, jj = k + 1 + idx % w;
            if (jj <= ii) A[ii][jj] -= A[ii][k] * A[jj][k];
        }
        __syncthreads();
    }
    if (tid == 0) {
        float ld = 0.f;
        for (int k = 0; k < N_; k++) ld += logf(A[k][k]);
        scal[SC_LD * B_ + b] = ld;
    }
    if (tid < N_) {
        int c = tid;
        for (int i = 0; i < N_; i++) {
            float s = (i == c) ? 1.f : 0.f;
            for (int k = c; k < i; k++) s -= A[i][k] * Y[k][c];
            Y[i][c] = (i >= c) ? s / A[i][i] : 0.f;
        }
    }
    __syncthreads();
    float ts = 0.f;
    for (int idx = tid; idx < N_ * N_; idx += 64) {
        float y = Y[idx >> 5][idx & 31];
        ts += y * y;
    }
    for (int off = 32; off > 0; off >>= 1) ts += __shfl_down(ts, off, 64);
    if (tid == 0) scal[SC_TI * B_ + b] = ts;
    if (tid == 0) {
        for (int i = N_ - 1; i >= 0; i--) {
            float s = eps[(size_t)b * N_ + i];
            for (int k = i + 1; k < N_; k++) s -= A[k][i] * dz[k];
            dz[i] = s / A[i][i];
        }
    }
    __syncthreads();
    if (tid < N_) {
        zsh[tid] = zst[(size_t)b * N_ + tid] + dz[tid];
        zs2[(size_t)b * N_ + tid] = zsh[tid];
    }
    __syncthreads();
    if (tid == 0) {
        float a0 = sigb[0], a1 = sigb[1];
        for (int k = 0; k < N_; k++) {
            a0 += zsh[k] * sigW[k * 2 + 0];
            a1 += zsh[k] * sigW[k * 2 + 1];
        }
        scal[SC_SP2 * B_ + b] = expf(a0);
        scal[SC_SV2 * B_ + b] = expf(a1);
    }
}

// ---------------------------------------------------------------------------
// dsq: d_sq = ||x||^2 - 2<x,b2> - <h2,Psum> - <h2,V> + <h2,w2b2> + ||b2||^2
// ---------------------------------------------------------------------------
__global__ __launch_bounds__(256) void dsq_kernel(
    const float* __restrict__ x, const float* __restrict__ b2,
    const float* __restrict__ hf, const float* __restrict__ Pp,
    const float* __restrict__ V, const float* __restrict__ w2b2,
    float* __restrict__ scal)
{
    const int b = blockIdx.x, tid = threadIdx.x;
    __shared__ float red[256];
    float xn = 0.f, xb2 = 0.f, b2n = 0.f;
    for (int d = tid; d < D_; d += 256) {
        float xv = x[(size_t)b * D_ + d];
        float bv = b2[d];
        xn += xv * xv; xb2 += xv * bv; b2n += bv * bv;
    }
    float hP = 0.f, hV = 0.f, hW = 0.f;
    for (int j = tid; j < H_; j += 256) {
        float h = hf[(size_t)b * H_ + j];
        float ps = 0.f;
#pragma unroll
        for (int s = 0; s < 8; s++) ps += Pp[(size_t)s * (64 * H_) + (size_t)b * H_ + j];
        hP += h * ps;
        hV += h * V[(size_t)b * H_ + j];
        hW += h * w2b2[j];
    }
    float vals[6] = {xn, xb2, b2n, hP, hV, hW};
    float res[6];
    for (int q = 0; q < 6; q++) {
        red[tid] = vals[q]; __syncthreads();
        for (int off = 128; off > 0; off >>= 1) {
            if (tid < off) red[tid] += red[tid + off];
            __syncthreads();
        }
        res[q] = red[0]; __syncthreads();
    }
    if (tid == 0)
        scal[SC_DSQ * B_ + b] = res[0] - 2.f * res[1] - res[3] - res[4] + res[5] + res[2];
}

// ---------------------------------------------------------------------------
// final: t = W1m2 @ V; chol(G2); d_proj; assemble output.
// ---------------------------------------------------------------------------
__global__ __launch_bounds__(256) void final_kernel(
    const float* __restrict__ V, const float* __restrict__ W1,
    const float* __restrict__ mask2, const float* __restrict__ G2,
    const float* __restrict__ scal, float* __restrict__ out)
{
    const int b = blockIdx.x, tid = threadIdx.x;
    __shared__ float A[N_][N_ + 1];
    __shared__ float red[256];
    __shared__ float t[N_], y[N_], sol[N_];
    const int n = tid >> 3, lane = tid & 7;
    float p = 0.f;
    for (int j = lane; j < H_; j += 8)
        p += W1[(size_t)n * H_ + j] * mask2[(size_t)b * H_ + j] * V[(size_t)b * H_ + j];
    red[tid] = p;
    for (int idx = tid; idx < N_ * N_; idx += 256)
        A[idx >> 5][idx & 31] = G2[(size_t)b * N_ * N_ + idx];
    __syncthreads();
    if (lane == 0) {
        float s = 0.f;
#pragma unroll
        for (int l = 0; l < 8; l++) s += red[n * 8 + l];
        t[n] = s;
    }
    __syncthreads();
    for (int k = 0; k < N_; k++) {
        if (tid == 0) A[k][k] = sqrtf(A[k][k]);
        __syncthreads();
        if (tid > k && tid < N_) A[tid][k] /= A[k][k];
        __syncthreads();
        int w = N_ - 1 - k;
        for (int idx = tid; idx < w * w; idx += 256) {
            int ii = k + 1 + idx / w, jj = k + 1 + idx % w;
            if (jj <= ii) A[ii][jj] -= A[ii][k] * A[jj][k];
        }
        __syncthreads();
    }
    if (tid == 0) {
        for (int i = 0; i < N_; i++) {
            float s = t[i];
            for (int k = 0; k < i; k++) s -= A[i][k] * y[k];
            y[i] = s / A[i][i];
        }
        for (int i = N_ - 1; i >= 0; i--) {
            float s = y[i];
            for (int k = i + 1; k < N_; k++) s -= A[k][i] * sol[k];
            sol[i] = s / A[i][i];
        }
        float dproj = 0.f;
        for (int i = 0; i < N_; i++) dproj += t[i] * sol[i];
        float sp2 = scal[SC_SP2 * B_ + b], sv2 = scal[SC_SV2 * B_ + b];
        float recon = scal[SC_DSQ * B_ + b] / (2.f * sv2 * sv2) +
                      dproj * (0.5f / (sp2 * sp2) - 0.5f / (sv2 * sv2)) +
                      (float)N_ * logf(sp2) + (float)(D_ - N_) * logf(sv2);
        float res = recon + 0.5f * scal[SC_ZN * B_ + b] + 0.5f * scal[SC_TI * B_ + b] +
                    scal[SC_LD * B_ + b];
        out[b] = res / (float)D_;
    }
}

// ---------------------------------------------------------------------------
extern "C" void kernel_launch(void* const* d_in, const int* in_sizes, int n_in,
                              void* d_out, int out_size, void* d_ws, size_t ws_size,
                              hipStream_t stream)
{
    const float* x     = (const float*)d_in[0];
    const float* eps   = (const float*)d_in[1];
    const float* encW1 = (const float*)d_in[2];
    const float* encb1 = (const float*)d_in[3];
    const float* encW2 = (const float*)d_in[4];
    const float* encb2 = (const float*)d_in[5];
    const float* decW1 = (const float*)d_in[6];
    const float* decb1 = (const float*)d_in[7];
    const float* decW2 = (const float*)d_in[8];
    const float* decb2 = (const float*)d_in[9];
    const float* sigW  = (const float*)d_in[10];
    const float* sigb  = (const float*)d_in[11];
    float* out = (float*)d_out;
    (void)in_sizes; (void)n_in; (void)out_size; (void)ws_size;

    float* ws = (float*)d_ws;
    size_t off = 0;
    auto allocf = [&](size_t nel) { float* p = ws + off; off += nel; return p; };
    auto allocb = [&](size_t nel) { u16* p = (u16*)(ws + off); off += nel / 2; return p; };

    u16*   w2b    = allocb((size_t)H_ * D_);      // 50.3 MB
    u16*   Sb     = allocb((size_t)H_ * H_);      // 8.4 MB
    u16*   wm     = allocb((size_t)B_ * N_ * H_); // 8.4 MB (reused mask1->mask2)
    u16*   Tb     = allocb((size_t)B_ * N_ * H_); // 8.4 MB (reused T1->T2)
    u16*   xb     = allocb((size_t)B_ * D_);      // 1.6 MB
    u16*   h2b    = allocb((size_t)B_ * H_);      // 0.26 MB
    float* h1p    = allocf((size_t)8 * B_ * H_);  // 4.2 MB
    float* Pp     = allocf((size_t)8 * B_ * H_);  // 4.2 MB
    float* h2f    = allocf((size_t)B_ * H_);
    float* mask2f = allocf((size_t)B_ * H_);
    float* V      = allocf((size_t)B_ * H_);
    float* w2b2   = allocf(H_);
    float* zst    = allocf((size_t)B_ * N_);
    float* zs2    = allocf((size_t)B_ * N_);
    float* G      = allocf((size_t)B_ * N_ * N_);
    float* G2     = allocf((size_t)B_ * N_ * N_);
    float* scal   = allocf(8 * B_);

    // conversions
    convW2_kernel<<<H_, 256, 0, stream>>>(decW2, decb2, w2b, w2b2);
    convX_kernel<<<(B_ * D_) / 1024, 256, 0, stream>>>(x, xb);
    // S = W2 W2^T (bf16 MFMA, symmetric)
    mfma128_kernel<1><<<dim3(16, 16), 256, 0, stream>>>(w2b, w2b, Sb, D_, H_);
    // h1 partials = xb @ encW1 (split-K=8, fp32 B transpose-converted)
    skinny_kernel<1, 0><<<dim3(H_ / 64, 8), 256, 0, stream>>>(
        xb, D_, encW1, H_, D_ / 8, H_, h1p, nullptr, nullptr, nullptr);
    // P partials = xb @ w2b^T
    skinny_kernel<0, 0><<<dim3(H_ / 64, 8), 256, 0, stream>>>(
        xb, D_, w2b, D_, D_ / 8, H_, Pp, nullptr, nullptr, nullptr);
    // z_star, sp, sv, ||z||^2
    zstar_kernel<<<B_, 256, 0, stream>>>(h1p, encb1, encW2, encb2, sigW, sigb, zst, scal);
    // wm1
    build_wm_kernel<0><<<B_, 256, 0, stream>>>(zst, decW1, decb1, wm, nullptr, nullptr, nullptr);
    // T1 = wm1 @ S
    mfma128_kernel<0><<<dim3(16, 16), 256, 0, stream>>>(wm, Sb, Tb, H_, H_);
    // G
    gbat_kernel<<<B_, 256, 0, stream>>>(Tb, wm, G);
    // Cholesky pipeline
    chol_kernel<<<B_, 64, 0, stream>>>(G, sigW, sigb, eps, zst, zs2, scal);
    // wm2 + h2 + mask2
    build_wm_kernel<1><<<B_, 256, 0, stream>>>(zs2, decW1, decb1, wm, h2b, h2f, mask2f);
    // T2 = wm2 @ S
    mfma128_kernel<0><<<dim3(16, 16), 256, 0, stream>>>(wm, Sb, Tb, H_, H_);
    // G2
    gbat_kernel<<<B_, 256, 0, stream>>>(Tb, wm, G2);
    // Q = h2 @ S ; V = Psum - Q - w2b2
    skinny_kernel<0, 1><<<dim3(H_ / 64, 1), 256, 0, stream>>>(
        h2b, H_, Sb, H_, H_, H_, nullptr, Pp, w2b2, V);
    // d_sq
    dsq_kernel<<<B_, 256, 0, stream>>>(x, decb2, h2f, Pp, V, w2b2, scal);
    // final
    final_kernel<<<B_, 256, 0, stream>>>(V, decW1, mask2f, G2, scal, out);
}

// Round 3
// 846.784 us; speedup vs baseline: 5.7512x; 1.2777x over previous
//
#include <hip/hip_runtime.h>
#include <math.h>
#include <stdint.h>

constexpr int B_ = 64;
constexpr int D_ = 12288;
constexpr int N_ = 32;
constexpr int H_ = 2048;

#define SC_SP  0
#define SC_SV  1
#define SC_SP2 2
#define SC_SV2 3
#define SC_LD  4
#define SC_TI  5
#define SC_ZN  6
#define SC_DSQ 7

typedef unsigned short u16;
typedef __bf16 bf16x8 __attribute__((ext_vector_type(8)));
typedef float f32x4 __attribute__((ext_vector_type(4)));
typedef float f4 __attribute__((ext_vector_type(4)));
typedef unsigned int u32x4 __attribute__((ext_vector_type(4)));
typedef unsigned int u32x2 __attribute__((ext_vector_type(2)));

__device__ inline u16 f2bf(float f) {
    union { float f; uint32_t u; } v; v.f = f;
    uint32_t u = v.u;
    u += 0x7fffu + ((u >> 16) & 1u);   // round-to-nearest-even
    return (u16)(u >> 16);
}
__device__ inline uint32_t pack2(float a, float b) {
    return (uint32_t)f2bf(a) | ((uint32_t)f2bf(b) << 16);
}
// decode triangular tile index t in [0,136) -> (by, bx) with bx >= by
__device__ inline void tri_decode(int t, int& by, int& bx) {
    int rem = t; by = 0;
    while (rem >= 16 - by) { rem -= 16 - by; by++; }
    bx = by + rem;
}

// ---------------------------------------------------------------------------
// convW2: decW2 (H x D fp32) -> w2b (bf16), and w2b2[h] = sum_d W2[h,d]*b2[d]
// ---------------------------------------------------------------------------
__global__ __launch_bounds__(256) void convW2_kernel(
    const float* __restrict__ W2, const float* __restrict__ b2,
    u16* __restrict__ w2b, float* __restrict__ w2b2)
{
    const int h = blockIdx.x, tid = threadIdx.x;
    const float* src = W2 + (size_t)h * D_;
    u16* dst = w2b + (size_t)h * D_;
    float s = 0.f;
    for (int d = tid * 4; d < D_; d += 1024) {
        f4 v = *reinterpret_cast<const f4*>(&src[d]);
        f4 bv = *reinterpret_cast<const f4*>(&b2[d]);
        uint32_t p0 = pack2(v[0], v[1]);
        uint32_t p1 = pack2(v[2], v[3]);
        *reinterpret_cast<uint32_t*>(&dst[d]) = p0;
        *reinterpret_cast<uint32_t*>(&dst[d + 2]) = p1;
        s += v[0] * bv[0] + v[1] * bv[1] + v[2] * bv[2] + v[3] * bv[3];
    }
    __shared__ float red[256];
    red[tid] = s; __syncthreads();
    for (int off = 128; off > 0; off >>= 1) {
        if (tid < off) red[tid] += red[tid + off];
        __syncthreads();
    }
    if (tid == 0) w2b2[h] = red[0];
}

__global__ __launch_bounds__(256) void convX_kernel(
    const float* __restrict__ x, u16* __restrict__ xb)
{
    int i = (blockIdx.x * 256 + threadIdx.x) * 4;
    f4 v = *reinterpret_cast<const f4*>(&x[i]);
    *reinterpret_cast<uint32_t*>(&xb[i]) = pack2(v[0], v[1]);
    *reinterpret_cast<uint32_t*>(&xb[i + 2]) = pack2(v[2], v[3]);
}

// ---------------------------------------------------------------------------
// mfmaS: split-K S = W2 W2^T.  grid (8 ksplits, 136 upper tiles).
// Writes fp32 partial slab[(tile*8+ks)*16384 + r*128 + c].
// ---------------------------------------------------------------------------
__global__ __launch_bounds__(256) void mfmaS_kernel(
    const u16* __restrict__ A, float* __restrict__ slab)
{
    const int ks = blockIdx.x;
    int by, bx; tri_decode(blockIdx.y, by, bx);
    const int m0 = by * 128, n0 = bx * 128, kb = ks * (D_ / 8);
    __shared__ u16 As[128 * 40];
    __shared__ u16 Bs[128 * 40];
    const int tid = threadIdx.x;
    const int w = tid >> 6, lane = tid & 63, quad = lane >> 4, l16 = lane & 15;
    const int moff = (w >> 1) * 64, noff = (w & 1) * 64;
    f32x4 acc[4][4];
#pragma unroll
    for (int i = 0; i < 4; i++)
#pragma unroll
        for (int j = 0; j < 4; j++) acc[i][j] = (f32x4){0.f, 0.f, 0.f, 0.f};

    for (int k0 = 0; k0 < D_ / 8; k0 += 32) {
#pragma unroll
        for (int it = 0; it < 2; it++) {
            int c = tid + it * 256;
            int row = c >> 2, k8 = (c & 3) * 8;
            *reinterpret_cast<u32x4*>(&As[row * 40 + k8]) =
                *reinterpret_cast<const u32x4*>(&A[(size_t)(m0 + row) * D_ + kb + k0 + k8]);
            *reinterpret_cast<u32x4*>(&Bs[row * 40 + k8]) =
                *reinterpret_cast<const u32x4*>(&A[(size_t)(n0 + row) * D_ + kb + k0 + k8]);
        }
        __syncthreads();
        bf16x8 a[4], bb[4];
#pragma unroll
        for (int t = 0; t < 4; t++) {
            a[t]  = *reinterpret_cast<const bf16x8*>(&As[(moff + t * 16 + l16) * 40 + quad * 8]);
            bb[t] = *reinterpret_cast<const bf16x8*>(&Bs[(noff + t * 16 + l16) * 40 + quad * 8]);
        }
#pragma unroll
        for (int mt = 0; mt < 4; mt++)
#pragma unroll
            for (int nt = 0; nt < 4; nt++)
                acc[mt][nt] = __builtin_amdgcn_mfma_f32_16x16x32_bf16(a[mt], bb[nt], acc[mt][nt], 0, 0, 0);
        __syncthreads();
    }
    float* out = slab + (((size_t)blockIdx.y * 8 + ks) << 14);
#pragma unroll
    for (int mt = 0; mt < 4; mt++)
#pragma unroll
        for (int nt = 0; nt < 4; nt++) {
            int r = moff + mt * 16 + quad * 4;
            int c = noff + nt * 16 + l16;
#pragma unroll
            for (int i = 0; i < 4; i++) out[(r + i) * 128 + c] = acc[mt][nt][i];
        }
}

// ---------------------------------------------------------------------------
// reduceS: sum 8 slabs -> bf16 S, mirrored via LDS transpose.
// ---------------------------------------------------------------------------
__global__ __launch_bounds__(256) void reduceS_kernel(
    const float* __restrict__ slab, u16* __restrict__ S)
{
    int by, bx; tri_decode(blockIdx.x, by, bx);
    const int i0 = by * 128, j0 = bx * 128;
    const int tid = threadIdx.x;
    __shared__ u16 tile[128][132];
    const float* base = slab + ((size_t)blockIdx.x * 8 << 14);
#pragma unroll
    for (int i = 0; i < 16; i++) {
        int e = i * 1024 + tid * 4;
        f4 s = (f4){0.f, 0.f, 0.f, 0.f};
#pragma unroll
        for (int ks = 0; ks < 8; ks++)
            s += *reinterpret_cast<const f4*>(&base[(size_t)ks * 16384 + e]);
        int r = e >> 7, c = e & 127;
        u32x2 p; p[0] = pack2(s[0], s[1]); p[1] = pack2(s[2], s[3]);
        *reinterpret_cast<u32x2*>(&S[(size_t)(i0 + r) * H_ + j0 + c]) = p;
        tile[r][c] = (u16)(p[0] & 0xffff); tile[r][c + 1] = (u16)(p[0] >> 16);
        tile[r][c + 2] = (u16)(p[1] & 0xffff); tile[r][c + 3] = (u16)(p[1] >> 16);
    }
    __syncthreads();
    if (by != bx) {
#pragma unroll
        for (int i = 0; i < 8; i++) {
            int idx = i * 256 + tid;
            int rr = idx >> 4, cc = (idx & 15) * 8;
            u32x4 v;
#pragma unroll
            for (int q = 0; q < 4; q++)
                v[q] = (uint32_t)tile[cc + 2 * q][rr] | ((uint32_t)tile[cc + 2 * q + 1][rr] << 16);
            *reinterpret_cast<u32x4*>(&S[(size_t)(j0 + rr) * H_ + i0 + cc]) = v;
        }
    }
}

// ---------------------------------------------------------------------------
// mfmaT: split-K=2 T = wm @ S^T (S sym).  grid (2, 256 tiles).
// ---------------------------------------------------------------------------
__global__ __launch_bounds__(256) void mfmaT_kernel(
    const u16* __restrict__ A, const u16* __restrict__ B, float* __restrict__ slab)
{
    const int ks = blockIdx.x;
    const int t = blockIdx.y;
    const int m0 = (t >> 4) * 128, n0 = (t & 15) * 128, kb = ks * (H_ / 2);
    __shared__ u16 As[128 * 40];
    __shared__ u16 Bs[128 * 40];
    const int tid = threadIdx.x;
    const int w = tid >> 6, lane = tid & 63, quad = lane >> 4, l16 = lane & 15;
    const int moff = (w >> 1) * 64, noff = (w & 1) * 64;
    f32x4 acc[4][4];
#pragma unroll
    for (int i = 0; i < 4; i++)
#pragma unroll
        for (int j = 0; j < 4; j++) acc[i][j] = (f32x4){0.f, 0.f, 0.f, 0.f};

    for (int k0 = 0; k0 < H_ / 2; k0 += 32) {
#pragma unroll
        for (int it = 0; it < 2; it++) {
            int c = tid + it * 256;
            int row = c >> 2, k8 = (c & 3) * 8;
            *reinterpret_cast<u32x4*>(&As[row * 40 + k8]) =
                *reinterpret_cast<const u32x4*>(&A[(size_t)(m0 + row) * H_ + kb + k0 + k8]);
            *reinterpret_cast<u32x4*>(&Bs[row * 40 + k8]) =
                *reinterpret_cast<const u32x4*>(&B[(size_t)(n0 + row) * H_ + kb + k0 + k8]);
        }
        __syncthreads();
        bf16x8 a[4], bb[4];
#pragma unroll
        for (int tt = 0; tt < 4; tt++) {
            a[tt]  = *reinterpret_cast<const bf16x8*>(&As[(moff + tt * 16 + l16) * 40 + quad * 8]);
            bb[tt] = *reinterpret_cast<const bf16x8*>(&Bs[(noff + tt * 16 + l16) * 40 + quad * 8]);
        }
#pragma unroll
        for (int mt = 0; mt < 4; mt++)
#pragma unroll
            for (int nt = 0; nt < 4; nt++)
                acc[mt][nt] = __builtin_amdgcn_mfma_f32_16x16x32_bf16(a[mt], bb[nt], acc[mt][nt], 0, 0, 0);
        __syncthreads();
    }
    float* out = slab + (((size_t)t * 2 + ks) << 14);
#pragma unroll
    for (int mt = 0; mt < 4; mt++)
#pragma unroll
        for (int nt = 0; nt < 4; nt++) {
            int r = moff + mt * 16 + quad * 4;
            int c = noff + nt * 16 + l16;
#pragma unroll
            for (int i = 0; i < 4; i++) out[(r + i) * 128 + c] = acc[mt][nt][i];
        }
}

__global__ __launch_bounds__(256) void reduceT_kernel(
    const float* __restrict__ slab, u16* __restrict__ T)
{
    const int t = blockIdx.x;
    const int m0 = (t >> 4) * 128, n0 = (t & 15) * 128;
    const int tid = threadIdx.x;
    const float* base = slab + ((size_t)t * 2 << 14);
#pragma unroll
    for (int i = 0; i < 16; i++) {
        int e = i * 1024 + tid * 4;
        f4 s = *reinterpret_cast<const f4*>(&base[e]) +
               *reinterpret_cast<const f4*>(&base[16384 + e]);
        int r = e >> 7, c = e & 127;
        u32x2 p; p[0] = pack2(s[0], s[1]); p[1] = pack2(s[2], s[3]);
        *reinterpret_cast<u32x2*>(&T[(size_t)(m0 + r) * H_ + n0 + c]) = p;
    }
}

// ---------------------------------------------------------------------------
// skinny64: C(64 x Nn) = A(64 x K bf16) * B^T, split-K over blockIdx.y.
// BMODE 0: B bf16 row-major.  BMODE 1: B fp32 K-major (transpose+cvt).
// EPI 0: fp32 partial slab.  EPI 1: V = sum(Pp) - acc - w2b2.
// ---------------------------------------------------------------------------
template <int BMODE, int EPI>
__global__ __launch_bounds__(256) void skinny_kernel(
    const u16* __restrict__ A, int lda,
    const void* __restrict__ Bp, int ldb,
    int Kchunk, int Nout,
    float* __restrict__ Cp,
    const float* __restrict__ Pp, const float* __restrict__ w2b2,
    float* __restrict__ V)
{
    const int n0 = blockIdx.x * 64;
    const int kbase = blockIdx.y * Kchunk;
    __shared__ u16 As[64 * 40];
    __shared__ u16 Bs[64 * 40];
    const int tid = threadIdx.x;
    const int w = tid >> 6, lane = tid & 63, quad = lane >> 4, l16 = lane & 15;
    f32x4 acc[4];
#pragma unroll
    for (int t = 0; t < 4; t++) acc[t] = (f32x4){0.f, 0.f, 0.f, 0.f};

    for (int kt = 0; kt < Kchunk; kt += 32) {
        const int k0 = kbase + kt;
        {
            int row = tid >> 2, k8 = (tid & 3) * 8;
            *reinterpret_cast<u32x4*>(&As[row * 40 + k8]) =
                *reinterpret_cast<const u32x4*>(&A[(size_t)row * lda + k0 + k8]);
        }
        if (BMODE == 0) {
            const u16* Bb = (const u16*)Bp;
            int row = tid >> 2, k8 = (tid & 3) * 8;
            *reinterpret_cast<u32x4*>(&Bs[row * 40 + k8]) =
                *reinterpret_cast<const u32x4*>(&Bb[(size_t)(n0 + row) * ldb + k0 + k8]);
        } else {
            const float* Bf = (const float*)Bp;
            int kk = tid >> 4, n4 = (tid & 15) * 4;
            f4 v0 = *reinterpret_cast<const f4*>(&Bf[(size_t)(k0 + kk) * ldb + n0 + n4]);
            f4 v1 = *reinterpret_cast<const f4*>(&Bf[(size_t)(k0 + kk + 16) * ldb + n0 + n4]);
#pragma unroll
            for (int i = 0; i < 4; i++) {
                Bs[(n4 + i) * 40 + kk] = f2bf(v0[i]);
                Bs[(n4 + i) * 40 + kk + 16] = f2bf(v1[i]);
            }
        }
        __syncthreads();
        bf16x8 bb = *reinterpret_cast<const bf16x8*>(&Bs[(w * 16 + l16) * 40 + quad * 8]);
#pragma unroll
        for (int mt = 0; mt < 4; mt++) {
            bf16x8 a = *reinterpret_cast<const bf16x8*>(&As[(mt * 16 + l16) * 40 + quad * 8]);
            acc[mt] = __builtin_amdgcn_mfma_f32_16x16x32_bf16(a, bb, acc[mt], 0, 0, 0);
        }
        __syncthreads();
    }
#pragma unroll
    for (int mt = 0; mt < 4; mt++)
#pragma unroll
        for (int i = 0; i < 4; i++) {
            int row = mt * 16 + quad * 4 + i;
            int col = n0 + w * 16 + l16;
            if (EPI == 0) {
                Cp[(size_t)blockIdx.y * 64 * Nout + (size_t)row * Nout + col] = acc[mt][i];
            } else {
                float ps = 0.f;
#pragma unroll
                for (int s = 0; s < 8; s++) ps += Pp[(size_t)s * 64 * Nout + (size_t)row * Nout + col];
                V[(size_t)row * Nout + col] = ps - acc[mt][i] - w2b2[col];
            }
        }
}

// ---------------------------------------------------------------------------
// gbat: split-K=4.  Gp[(ks*64+b)*1024 + r*32+c] partial of T_b wm_b^T.
// ---------------------------------------------------------------------------
__global__ __launch_bounds__(256) void gbat_kernel(
    const u16* __restrict__ T, const u16* __restrict__ wm, float* __restrict__ Gp)
{
    const int ks = blockIdx.x, b = blockIdx.y, tid = threadIdx.x;
    const int w = tid >> 6, lane = tid & 63, quad = lane >> 4, l16 = lane & 15;
    const int kb = ks * (H_ / 4);
    const u16* Ta = T + ((size_t)b * 32 + (w >> 1) * 16 + l16) * H_ + kb + quad * 8;
    const u16* Wb = wm + ((size_t)b * 32 + (w & 1) * 16 + l16) * H_ + kb + quad * 8;
    f32x4 acc = (f32x4){0.f, 0.f, 0.f, 0.f};
    for (int k = 0; k < H_ / 4; k += 32) {
        bf16x8 a  = *reinterpret_cast<const bf16x8*>(Ta + k);
        bf16x8 bb = *reinterpret_cast<const bf16x8*>(Wb + k);
        acc = __builtin_amdgcn_mfma_f32_16x16x32_bf16(a, bb, acc, 0, 0, 0);
    }
    const int row = (w >> 1) * 16 + quad * 4, col = (w & 1) * 16 + l16;
#pragma unroll
    for (int i = 0; i < 4; i++)
        Gp[((size_t)ks * 64 + b) * 1024 + (size_t)(row + i) * 32 + col] = acc[i];
}

// ---------------------------------------------------------------------------
__global__ __launch_bounds__(256) void zstar_kernel(
    const float* __restrict__ h1p, const float* __restrict__ encb1,
    const float* __restrict__ encW2, const float* __restrict__ encb2,
    const float* __restrict__ sigW, const float* __restrict__ sigb,
    float* __restrict__ zst, float* __restrict__ scal)
{
    const int b = blockIdx.x, tid = threadIdx.x;
    __shared__ float hs[H_];
    __shared__ float red[256];
    __shared__ float zsm[N_];
    for (int j = tid; j < H_; j += 256) {
        float s = encb1[j];
#pragma unroll
        for (int t = 0; t < 8; t++) s += h1p[(size_t)t * (64 * H_) + (size_t)b * H_ + j];
        hs[j] = s > 0.f ? s : 0.f;
    }
    __syncthreads();
    const int n = tid & 31, g = tid >> 5;
    float p = 0.f;
    for (int j = g; j < H_; j += 8) p += hs[j] * encW2[j * 32 + n];
    red[tid] = p;
    __syncthreads();
    if (tid < 32) {
        float s = encb2[tid];
#pragma unroll
        for (int t = 0; t < 8; t++) s += red[t * 32 + tid];
        zsm[tid] = s;
        zst[(size_t)b * N_ + tid] = s;
    }
    __syncthreads();
    if (tid == 0) {
        float zn = 0.f, a0 = sigb[0], a1 = sigb[1];
        for (int k = 0; k < N_; k++) {
            zn += zsm[k] * zsm[k];
            a0 += zsm[k] * sigW[k * 2 + 0];
            a1 += zsm[k] * sigW[k * 2 + 1];
        }
        scal[SC_SP * B_ + b] = expf(a0);
        scal[SC_SV * B_ + b] = expf(a1);
        scal[SC_ZN * B_ + b] = zn;
    }
}

// ---------------------------------------------------------------------------
// build_wm: grid (2 parts, B).  Each thread owns 4 consecutive j.
// ---------------------------------------------------------------------------
template <int HOUT>
__global__ __launch_bounds__(256) void build_wm_kernel(
    const float* __restrict__ z, const float* __restrict__ W1,
    const float* __restrict__ b1, u16* __restrict__ wm,
    u16* __restrict__ hb, float* __restrict__ hf, float* __restrict__ maskf)
{
    const int b = blockIdx.y;
    const int j = blockIdx.x * 1024 + threadIdx.x * 4;
    __shared__ float zs[N_];
    if (threadIdx.x < N_) zs[threadIdx.x] = z[(size_t)b * N_ + threadIdx.x];
    __syncthreads();
    f4 pre = *reinterpret_cast<const f4*>(&b1[j]);
#pragma unroll
    for (int k = 0; k < N_; k++) {
        f4 w = *reinterpret_cast<const f4*>(&W1[(size_t)k * H_ + j]);
        pre += zs[k] * w;
    }
    f4 m;
#pragma unroll
    for (int i = 0; i < 4; i++) m[i] = pre[i] > 0.f ? 1.f : 0.f;
    if (HOUT) {
        f4 h;
#pragma unroll
        for (int i = 0; i < 4; i++) h[i] = pre[i] > 0.f ? pre[i] : 0.f;
        *reinterpret_cast<f4*>(&hf[(size_t)b * H_ + j]) = h;
        *reinterpret_cast<f4*>(&maskf[(size_t)b * H_ + j]) = m;
        u32x2 hp; hp[0] = pack2(h[0], h[1]); hp[1] = pack2(h[2], h[3]);
        *reinterpret_cast<u32x2*>(&hb[(size_t)b * H_ + j]) = hp;
    }
#pragma unroll 4
    for (int n = 0; n < N_; n++) {
        f4 w = *reinterpret_cast<const f4*>(&W1[(size_t)n * H_ + j]);
        u32x2 p; p[0] = pack2(w[0] * m[0], w[1] * m[1]); p[1] = pack2(w[2] * m[2], w[3] * m[3]);
        *reinterpret_cast<u32x2*>(&wm[((size_t)b * N_ + n) * H_ + j]) = p;
    }
}

// ---------------------------------------------------------------------------
__global__ __launch_bounds__(64) void chol_kernel(
    const float* __restrict__ Gp, const float* __restrict__ sigW,
    const float* __restrict__ sigb, const float* __restrict__ eps,
    const float* __restrict__ zst, float* __restrict__ zs2,
    float* __restrict__ scal)
{
    const int b = blockIdx.x, tid = threadIdx.x;
    __shared__ float A[N_][N_ + 1];
    __shared__ float Y[N_][N_ + 1];
    __shared__ float zsh[N_], dz[N_];
    const float sp = scal[SC_SP * B_ + b];
    const float isp2 = 1.f / (sp * sp);
    for (int idx = tid; idx < N_ * N_; idx += 64) {
        int i = idx >> 5, j = idx & 31;
        float g = 0.f;
#pragma unroll
        for (int ks = 0; ks < 4; ks++) g += Gp[((size_t)ks * 64 + b) * 1024 + idx];
        float st = 0.5f * ((float)N_ * sigW[i * 2] * sigW[j * 2] +
                           (float)(D_ - N_) * sigW[i * 2 + 1] * sigW[j * 2 + 1]);
        A[i][j] = g * isp2 + st + (i == j ? 1.f : 0.f);
    }
    __syncthreads();
    for (int k = 0; k < N_; k++) {
        if (tid == 0) A[k][k] = sqrtf(A[k][k]);
        __syncthreads();
        if (tid > k && tid < N_) A[tid][k] /= A[k][k];
        __syncthreads();
        int w = N_ - 1 - k;
        for (int idx = tid; idx < w * w; idx += 64) {
            int ii = k + 1 + idx / w, jj = k + 1 + idx % w;
            if (jj <= ii) A[ii][jj] -= A[ii][k] * A[jj][k];
        }
        __syncthreads();
    }
    if (tid == 0) {
        float ld = 0.f;
        for (int k = 0; k < N_; k++) ld += logf(A[k][k]);
        scal[SC_LD * B_ + b] = ld;
    }
    if (tid < N_) {
        int c = tid;
        for (int i = 0; i < N_; i++) {
            float s = (i == c) ? 1.f : 0.f;
            for (int k = c; k < i; k++) s -= A[i][k] * Y[k][c];
            Y[i][c] = (i >= c) ? s / A[i][i] : 0.f;
        }
    }
    __syncthreads();
    float ts = 0.f;
    for (int idx = tid; idx < N_ * N_; idx += 64) {
        float y = Y[idx >> 5][idx & 31];
        ts += y * y;
    }
    for (int off = 32; off > 0; off >>= 1) ts += __shfl_down(ts, off, 64);
    if (tid == 0) scal[SC_TI * B_ + b] = ts;
    if (tid == 0) {
        for (int i = N_ - 1; i >= 0; i--) {
            float s = eps[(size_t)b * N_ + i];
            for (int k = i + 1; k < N_; k++) s -= A[k][i] * dz[k];
            dz[i] = s / A[i][i];
        }
    }
    __syncthreads();
    if (tid < N_) {
        zsh[tid] = zst[(size_t)b * N_ + tid] + dz[tid];
        zs2[(size_t)b * N_ + tid] = zsh[tid];
    }
    __syncthreads();
    if (tid == 0) {
        float a0 = sigb[0], a1 = sigb[1];
        for (int k = 0; k < N_; k++) {
            a0 += zsh[k] * sigW[k * 2 + 0];
            a1 += zsh[k] * sigW[k * 2 + 1];
        }
        scal[SC_SP2 * B_ + b] = expf(a0);
        scal[SC_SV2 * B_ + b] = expf(a1);
    }
}

// ---------------------------------------------------------------------------
__global__ __launch_bounds__(256) void dsq_kernel(
    const float* __restrict__ x, const float* __restrict__ b2,
    const float* __restrict__ hf, const float* __restrict__ Pp,
    const float* __restrict__ V, const float* __restrict__ w2b2,
    float* __restrict__ scal)
{
    const int b = blockIdx.x, tid = threadIdx.x;
    __shared__ float red[256];
    float xn = 0.f, xb2 = 0.f, b2n = 0.f;
    for (int d = tid; d < D_; d += 256) {
        float xv = x[(size_t)b * D_ + d];
        float bv = b2[d];
        xn += xv * xv; xb2 += xv * bv; b2n += bv * bv;
    }
    float hP = 0.f, hV = 0.f, hW = 0.f;
    for (int j = tid; j < H_; j += 256) {
        float h = hf[(size_t)b * H_ + j];
        float ps = 0.f;
#pragma unroll
        for (int s = 0; s < 8; s++) ps += Pp[(size_t)s * (64 * H_) + (size_t)b * H_ + j];
        hP += h * ps;
        hV += h * V[(size_t)b * H_ + j];
        hW += h * w2b2[j];
    }
    float vals[6] = {xn, xb2, b2n, hP, hV, hW};
    float res[6];
    for (int q = 0; q < 6; q++) {
        red[tid] = vals[q]; __syncthreads();
        for (int off = 128; off > 0; off >>= 1) {
            if (tid < off) red[tid] += red[tid + off];
            __syncthreads();
        }
        res[q] = red[0]; __syncthreads();
    }
    if (tid == 0)
        scal[SC_DSQ * B_ + b] = res[0] - 2.f * res[1] - res[3] - res[4] + res[5] + res[2];
}

// ---------------------------------------------------------------------------
// final: t = W1m2 @ V (coalesced, waves own n's); chol(G2 slabs); output.
// ---------------------------------------------------------------------------
__global__ __launch_bounds__(256) void final_kernel(
    const float* __restrict__ V, const float* __restrict__ W1,
    const float* __restrict__ mask2, const float* __restrict__ G2p,
    const float* __restrict__ scal, float* __restrict__ out)
{
    const int b = blockIdx.x, tid = threadIdx.x;
    __shared__ float mv[H_];
    __shared__ float A[N_][N_ + 1];
    __shared__ float t[N_], y[N_], sol[N_];
    for (int j = tid; j < H_; j += 256)
        mv[j] = mask2[(size_t)b * H_ + j] * V[(size_t)b * H_ + j];
    for (int idx = tid; idx < N_ * N_; idx += 256) {
        float g = 0.f;
#pragma unroll
        for (int ks = 0; ks < 4; ks++) g += G2p[((size_t)ks * 64 + b) * 1024 + idx];
        A[idx >> 5][idx & 31] = g;
    }
    __syncthreads();
    const int w = tid >> 6, lane = tid & 63;
#pragma unroll
    for (int ni = 0; ni < 8; ni++) {
        int n = w * 8 + ni;
        float s = 0.f;
        for (int j = lane; j < H_; j += 64) s += W1[(size_t)n * H_ + j] * mv[j];
        for (int off = 32; off > 0; off >>= 1) s += __shfl_down(s, off, 64);
        if (lane == 0) t[n] = s;
    }
    __syncthreads();
    for (int k = 0; k < N_; k++) {
        if (tid == 0) A[k][k] = sqrtf(A[k][k]);
        __syncthreads();
        if (tid > k && tid < N_) A[tid][k] /= A[k][k];
        __syncthreads();
        int ww = N_ - 1 - k;
        for (int idx = tid; idx < ww * ww; idx += 256) {
            int ii = k + 1 + idx / ww, jj = k + 1 + idx % ww;
            if (jj <= ii) A[ii][jj] -= A[ii][k] * A[jj][k];
        }
        __syncthreads();
    }
    if (tid == 0) {
        for (int i = 0; i < N_; i++) {
            float s = t[i];
            for (int k = 0; k < i; k++) s -= A[i][k] * y[k];
            y[i] = s / A[i][i];
        }
        for (int i = N_ - 1; i >= 0; i--) {
            float s = y[i];
            for (int k = i + 1; k < N_; k++) s -= A[k][i] * sol[k];
            sol[i] = s / A[i][i];
        }
        float dproj = 0.f;
        for (int i = 0; i < N_; i++) dproj += t[i] * sol[i];
        float sp2 = scal[SC_SP2 * B_ + b], sv2 = scal[SC_SV2 * B_ + b];
        float recon = scal[SC_DSQ * B_ + b] / (2.f * sv2 * sv2) +
                      dproj * (0.5f / (sp2 * sp2) - 0.5f / (sv2 * sv2)) +
                      (float)N_ * logf(sp2) + (float)(D_ - N_) * logf(sv2);
        float res = recon + 0.5f * scal[SC_ZN * B_ + b] + 0.5f * scal[SC_TI * B_ + b] +
                    scal[SC_LD * B_ + b];
        out[b] = res / (float)D_;
    }
}

// ---------------------------------------------------------------------------
extern "C" void kernel_launch(void* const* d_in, const int* in_sizes, int n_in,
                              void* d_out, int out_size, void* d_ws, size_t ws_size,
                              hipStream_t stream)
{
    const float* x     = (const float*)d_in[0];
    const float* eps   = (const float*)d_in[1];
    const float* encW1 = (const float*)d_in[2];
    const float* encb1 = (const float*)d_in[3];
    const float* encW2 = (const float*)d_in[4];
    const float* encb2 = (const float*)d_in[5];
    const float* decW1 = (const float*)d_in[6];
    const float* decb1 = (const float*)d_in[7];
    const float* decW2 = (const float*)d_in[8];
    const float* decb2 = (const float*)d_in[9];
    const float* sigW  = (const float*)d_in[10];
    const float* sigb  = (const float*)d_in[11];
    float* out = (float*)d_out;
    (void)in_sizes; (void)n_in; (void)out_size; (void)ws_size;

    float* ws = (float*)d_ws;
    size_t off = 0;
    auto allocf = [&](size_t nel) { float* p = ws + off; off += nel; return p; };
    auto allocb = [&](size_t nel) { u16* p = (u16*)(ws + off); off += nel / 2; return p; };

    u16*   w2b    = allocb((size_t)H_ * D_);
    u16*   Sb     = allocb((size_t)H_ * H_);
    u16*   wm     = allocb((size_t)B_ * N_ * H_);
    u16*   Tb     = allocb((size_t)B_ * N_ * H_);
    u16*   xb     = allocb((size_t)B_ * D_);
    u16*   h2b    = allocb((size_t)B_ * H_);
    float* h1p    = allocf((size_t)8 * B_ * H_);
    float* Pp     = allocf((size_t)8 * B_ * H_);
    float* h2f    = allocf((size_t)B_ * H_);
    float* mask2f = allocf((size_t)B_ * H_);
    float* V      = allocf((size_t)B_ * H_);
    float* w2b2   = allocf(H_);
    float* zst    = allocf((size_t)B_ * N_);
    float* zs2    = allocf((size_t)B_ * N_);
    float* Gp     = allocf((size_t)4 * B_ * N_ * N_);
    float* G2p    = allocf((size_t)4 * B_ * N_ * N_);
    float* scal   = allocf(8 * B_);
    float* slab   = allocf((size_t)136 * 8 * 16384);  // S slabs; reused for T slabs

    convW2_kernel<<<H_, 256, 0, stream>>>(decW2, decb2, w2b, w2b2);
    convX_kernel<<<(B_ * D_) / 1024, 256, 0, stream>>>(x, xb);
    // S = W2 W2^T, split-K=8
    mfmaS_kernel<<<dim3(8, 136), 256, 0, stream>>>(w2b, slab);
    reduceS_kernel<<<136, 256, 0, stream>>>(slab, Sb);
    // h1 partials = xb @ encW1 (split-K=8)
    skinny_kernel<1, 0><<<dim3(H_ / 64, 8), 256, 0, stream>>>(
        xb, D_, encW1, H_, D_ / 8, H_, h1p, nullptr, nullptr, nullptr);
    // P partials = xb @ w2b^T
    skinny_kernel<0, 0><<<dim3(H_ / 64, 8), 256, 0, stream>>>(
        xb, D_, w2b, D_, D_ / 8, H_, Pp, nullptr, nullptr, nullptr);
    zstar_kernel<<<B_, 256, 0, stream>>>(h1p, encb1, encW2, encb2, sigW, sigb, zst, scal);
    build_wm_kernel<0><<<dim3(2, B_), 256, 0, stream>>>(zst, decW1, decb1, wm, nullptr, nullptr, nullptr);
    // T1 = wm1 @ S, split-K=2
    mfmaT_kernel<<<dim3(2, 256), 256, 0, stream>>>(wm, Sb, slab);
    reduceT_kernel<<<256, 256, 0, stream>>>(slab, Tb);
    gbat_kernel<<<dim3(4, B_), 256, 0, stream>>>(Tb, wm, Gp);
    chol_kernel<<<B_, 64, 0, stream>>>(Gp, sigW, sigb, eps, zst, zs2, scal);
    build_wm_kernel<1><<<dim3(2, B_), 256, 0, stream>>>(zs2, decW1, decb1, wm, h2b, h2f, mask2f);
    // T2 = wm2 @ S
    mfmaT_kernel<<<dim3(2, 256), 256, 0, stream>>>(wm, Sb, slab);
    reduceT_kernel<<<256, 256, 0, stream>>>(slab, Tb);
    gbat_kernel<<<dim3(4, B_), 256, 0, stream>>>(Tb, wm, G2p);
    // Q = h2 @ S ; V = Psum - Q - w2b2
    skinny_kernel<0, 1><<<dim3(H_ / 64, 1), 256, 0, stream>>>(
        h2b, H_, Sb, H_, H_, H_, nullptr, Pp, w2b2, V);
    dsq_kernel<<<B_, 256, 0, stream>>>(x, decb2, h2f, Pp, V, w2b2, scal);
    final_kernel<<<B_, 256, 0, stream>>>(V, decW1, mask2f, G2p, scal, out);
}

// Round 4
// 766.263 us; speedup vs baseline: 6.3556x; 1.1051x over previous
//
#include <hip/hip_runtime.h>
#include <math.h>
#include <stdint.h>

constexpr int B_ = 64;
constexpr int D_ = 12288;
constexpr int N_ = 32;
constexpr int H_ = 2048;

#define SC_SP  0
#define SC_SV  1
#define SC_SP2 2
#define SC_SV2 3
#define SC_LD  4
#define SC_TI  5
#define SC_ZN  6
#define SC_DSQ 7

typedef unsigned short u16;
typedef __bf16 bf16x8 __attribute__((ext_vector_type(8)));
typedef float f32x4 __attribute__((ext_vector_type(4)));
typedef float f4 __attribute__((ext_vector_type(4)));
typedef unsigned int u32x4 __attribute__((ext_vector_type(4)));
typedef unsigned int u32x2 __attribute__((ext_vector_type(2)));

__device__ inline u16 f2bf(float f) {
    union { float f; uint32_t u; } v; v.f = f;
    uint32_t u = v.u;
    u += 0x7fffu + ((u >> 16) & 1u);   // round-to-nearest-even
    return (u16)(u >> 16);
}
__device__ inline uint32_t pack2(float a, float b) {
    return (uint32_t)f2bf(a) | ((uint32_t)f2bf(b) << 16);
}
__device__ inline float bflo(uint32_t p) { union {uint32_t u; float f;} c; c.u = p << 16; return c.f; }
__device__ inline float bfhi(uint32_t p) { union {uint32_t u; float f;} c; c.u = p & 0xffff0000u; return c.f; }
// decode triangular tile index t in [0,136) -> (by, bx) with bx >= by
__device__ inline void tri_decode(int t, int& by, int& bx) {
    int rem = t; by = 0;
    while (rem >= 16 - by) { rem -= 16 - by; by++; }
    bx = by + rem;
}

// ---------------------------------------------------------------------------
// convW2: decW2 (H x D fp32) -> w2b (bf16), and w2b2[h] = sum_d W2[h,d]*b2[d]
// ---------------------------------------------------------------------------
__global__ __launch_bounds__(256) void convW2_kernel(
    const float* __restrict__ W2, const float* __restrict__ b2,
    u16* __restrict__ w2b, float* __restrict__ w2b2)
{
    const int h = blockIdx.x, tid = threadIdx.x;
    const float* src = W2 + (size_t)h * D_;
    u16* dst = w2b + (size_t)h * D_;
    float s = 0.f;
    for (int d = tid * 4; d < D_; d += 1024) {
        f4 v = *reinterpret_cast<const f4*>(&src[d]);
        f4 bv = *reinterpret_cast<const f4*>(&b2[d]);
        uint32_t p0 = pack2(v[0], v[1]);
        uint32_t p1 = pack2(v[2], v[3]);
        *reinterpret_cast<uint32_t*>(&dst[d]) = p0;
        *reinterpret_cast<uint32_t*>(&dst[d + 2]) = p1;
        s += v[0] * bv[0] + v[1] * bv[1] + v[2] * bv[2] + v[3] * bv[3];
    }
    __shared__ float red[256];
    red[tid] = s; __syncthreads();
    for (int off = 128; off > 0; off >>= 1) {
        if (tid < off) red[tid] += red[tid + off];
        __syncthreads();
    }
    if (tid == 0) w2b2[h] = red[0];
}

__global__ __launch_bounds__(256) void convX_kernel(
    const float* __restrict__ x, u16* __restrict__ xb)
{
    int i = (blockIdx.x * 256 + threadIdx.x) * 4;
    f4 v = *reinterpret_cast<const f4*>(&x[i]);
    *reinterpret_cast<uint32_t*>(&xb[i]) = pack2(v[0], v[1]);
    *reinterpret_cast<uint32_t*>(&xb[i + 2]) = pack2(v[2], v[3]);
}

// ---------------------------------------------------------------------------
// mfmaS: split-K S = W2 W2^T.  grid (8 ksplits, 136 upper tiles).
// ---------------------------------------------------------------------------
__global__ __launch_bounds__(256) void mfmaS_kernel(
    const u16* __restrict__ A, float* __restrict__ slab)
{
    const int ks = blockIdx.x;
    int by, bx; tri_decode(blockIdx.y, by, bx);
    const int m0 = by * 128, n0 = bx * 128, kb = ks * (D_ / 8);
    __shared__ u16 As[128 * 40];
    __shared__ u16 Bs[128 * 40];
    const int tid = threadIdx.x;
    const int w = tid >> 6, lane = tid & 63, quad = lane >> 4, l16 = lane & 15;
    const int moff = (w >> 1) * 64, noff = (w & 1) * 64;
    f32x4 acc[4][4];
#pragma unroll
    for (int i = 0; i < 4; i++)
#pragma unroll
        for (int j = 0; j < 4; j++) acc[i][j] = (f32x4){0.f, 0.f, 0.f, 0.f};

    for (int k0 = 0; k0 < D_ / 8; k0 += 32) {
#pragma unroll
        for (int it = 0; it < 2; it++) {
            int c = tid + it * 256;
            int row = c >> 2, k8 = (c & 3) * 8;
            *reinterpret_cast<u32x4*>(&As[row * 40 + k8]) =
                *reinterpret_cast<const u32x4*>(&A[(size_t)(m0 + row) * D_ + kb + k0 + k8]);
            *reinterpret_cast<u32x4*>(&Bs[row * 40 + k8]) =
                *reinterpret_cast<const u32x4*>(&A[(size_t)(n0 + row) * D_ + kb + k0 + k8]);
        }
        __syncthreads();
        bf16x8 a[4], bb[4];
#pragma unroll
        for (int t = 0; t < 4; t++) {
            a[t]  = *reinterpret_cast<const bf16x8*>(&As[(moff + t * 16 + l16) * 40 + quad * 8]);
            bb[t] = *reinterpret_cast<const bf16x8*>(&Bs[(noff + t * 16 + l16) * 40 + quad * 8]);
        }
#pragma unroll
        for (int mt = 0; mt < 4; mt++)
#pragma unroll
            for (int nt = 0; nt < 4; nt++)
                acc[mt][nt] = __builtin_amdgcn_mfma_f32_16x16x32_bf16(a[mt], bb[nt], acc[mt][nt], 0, 0, 0);
        __syncthreads();
    }
    float* out = slab + (((size_t)blockIdx.y * 8 + ks) << 14);
#pragma unroll
    for (int mt = 0; mt < 4; mt++)
#pragma unroll
        for (int nt = 0; nt < 4; nt++) {
            int r = moff + mt * 16 + quad * 4;
            int c = noff + nt * 16 + l16;
#pragma unroll
            for (int i = 0; i < 4; i++) out[(r + i) * 128 + c] = acc[mt][nt][i];
        }
}

// ---------------------------------------------------------------------------
// reduceS: sum 8 slabs -> bf16 S, mirrored via LDS transpose.
// ---------------------------------------------------------------------------
__global__ __launch_bounds__(256) void reduceS_kernel(
    const float* __restrict__ slab, u16* __restrict__ S)
{
    int by, bx; tri_decode(blockIdx.x, by, bx);
    const int i0 = by * 128, j0 = bx * 128;
    const int tid = threadIdx.x;
    __shared__ u16 tile[128][132];
    const float* base = slab + ((size_t)blockIdx.x * 8 << 14);
#pragma unroll
    for (int i = 0; i < 16; i++) {
        int e = i * 1024 + tid * 4;
        f4 s = (f4){0.f, 0.f, 0.f, 0.f};
#pragma unroll
        for (int ks = 0; ks < 8; ks++)
            s += *reinterpret_cast<const f4*>(&base[(size_t)ks * 16384 + e]);
        int r = e >> 7, c = e & 127;
        u32x2 p; p[0] = pack2(s[0], s[1]); p[1] = pack2(s[2], s[3]);
        *reinterpret_cast<u32x2*>(&S[(size_t)(i0 + r) * H_ + j0 + c]) = p;
        tile[r][c] = (u16)(p[0] & 0xffff); tile[r][c + 1] = (u16)(p[0] >> 16);
        tile[r][c + 2] = (u16)(p[1] & 0xffff); tile[r][c + 3] = (u16)(p[1] >> 16);
    }
    __syncthreads();
    if (by != bx) {
#pragma unroll
        for (int i = 0; i < 8; i++) {
            int idx = i * 256 + tid;
            int rr = idx >> 4, cc = (idx & 15) * 8;
            u32x4 v;
#pragma unroll
            for (int q = 0; q < 4; q++)
                v[q] = (uint32_t)tile[cc + 2 * q][rr] | ((uint32_t)tile[cc + 2 * q + 1][rr] << 16);
            *reinterpret_cast<u32x4*>(&S[(size_t)(j0 + rr) * H_ + i0 + cc]) = v;
        }
    }
}

// ---------------------------------------------------------------------------
// mfmaT: split-K=2 T = wm @ S^T (S sym).  grid (2, 256 tiles).
// ---------------------------------------------------------------------------
__global__ __launch_bounds__(256) void mfmaT_kernel(
    const u16* __restrict__ A, const u16* __restrict__ B, float* __restrict__ slab)
{
    const int ks = blockIdx.x;
    const int t = blockIdx.y;
    const int m0 = (t >> 4) * 128, n0 = (t & 15) * 128, kb = ks * (H_ / 2);
    __shared__ u16 As[128 * 40];
    __shared__ u16 Bs[128 * 40];
    const int tid = threadIdx.x;
    const int w = tid >> 6, lane = tid & 63, quad = lane >> 4, l16 = lane & 15;
    const int moff = (w >> 1) * 64, noff = (w & 1) * 64;
    f32x4 acc[4][4];
#pragma unroll
    for (int i = 0; i < 4; i++)
#pragma unroll
        for (int j = 0; j < 4; j++) acc[i][j] = (f32x4){0.f, 0.f, 0.f, 0.f};

    for (int k0 = 0; k0 < H_ / 2; k0 += 32) {
#pragma unroll
        for (int it = 0; it < 2; it++) {
            int c = tid + it * 256;
            int row = c >> 2, k8 = (c & 3) * 8;
            *reinterpret_cast<u32x4*>(&As[row * 40 + k8]) =
                *reinterpret_cast<const u32x4*>(&A[(size_t)(m0 + row) * H_ + kb + k0 + k8]);
            *reinterpret_cast<u32x4*>(&Bs[row * 40 + k8]) =
                *reinterpret_cast<const u32x4*>(&B[(size_t)(n0 + row) * H_ + kb + k0 + k8]);
        }
        __syncthreads();
        bf16x8 a[4], bb[4];
#pragma unroll
        for (int tt = 0; tt < 4; tt++) {
            a[tt]  = *reinterpret_cast<const bf16x8*>(&As[(moff + tt * 16 + l16) * 40 + quad * 8]);
            bb[tt] = *reinterpret_cast<const bf16x8*>(&Bs[(noff + tt * 16 + l16) * 40 + quad * 8]);
        }
#pragma unroll
        for (int mt = 0; mt < 4; mt++)
#pragma unroll
            for (int nt = 0; nt < 4; nt++)
                acc[mt][nt] = __builtin_amdgcn_mfma_f32_16x16x32_bf16(a[mt], bb[nt], acc[mt][nt], 0, 0, 0);
        __syncthreads();
    }
    float* out = slab + (((size_t)t * 2 + ks) << 14);
#pragma unroll
    for (int mt = 0; mt < 4; mt++)
#pragma unroll
        for (int nt = 0; nt < 4; nt++) {
            int r = moff + mt * 16 + quad * 4;
            int c = noff + nt * 16 + l16;
#pragma unroll
            for (int i = 0; i < 4; i++) out[(r + i) * 128 + c] = acc[mt][nt][i];
        }
}

__global__ __launch_bounds__(256) void reduceT_kernel(
    const float* __restrict__ slab, u16* __restrict__ T)
{
    const int t = blockIdx.x;
    const int m0 = (t >> 4) * 128, n0 = (t & 15) * 128;
    const int tid = threadIdx.x;
    const float* base = slab + ((size_t)t * 2 << 14);
#pragma unroll
    for (int i = 0; i < 16; i++) {
        int e = i * 1024 + tid * 4;
        f4 s = *reinterpret_cast<const f4*>(&base[e]) +
               *reinterpret_cast<const f4*>(&base[16384 + e]);
        int r = e >> 7, c = e & 127;
        u32x2 p; p[0] = pack2(s[0], s[1]); p[1] = pack2(s[2], s[3]);
        *reinterpret_cast<u32x2*>(&T[(size_t)(m0 + r) * H_ + n0 + c]) = p;
    }
}

// ---------------------------------------------------------------------------
// skinny64: C(64 x Nn) = A(64 x K bf16) * B^T, split-K over blockIdx.y.
// ---------------------------------------------------------------------------
template <int BMODE, int EPI>
__global__ __launch_bounds__(256) void skinny_kernel(
    const u16* __restrict__ A, int lda,
    const void* __restrict__ Bp, int ldb,
    int Kchunk, int Nout,
    float* __restrict__ Cp,
    const float* __restrict__ Pp, const float* __restrict__ w2b2,
    float* __restrict__ V)
{
    const int n0 = blockIdx.x * 64;
    const int kbase = blockIdx.y * Kchunk;
    __shared__ u16 As[64 * 40];
    __shared__ u16 Bs[64 * 40];
    const int tid = threadIdx.x;
    const int w = tid >> 6, lane = tid & 63, quad = lane >> 4, l16 = lane & 15;
    f32x4 acc[4];
#pragma unroll
    for (int t = 0; t < 4; t++) acc[t] = (f32x4){0.f, 0.f, 0.f, 0.f};

    for (int kt = 0; kt < Kchunk; kt += 32) {
        const int k0 = kbase + kt;
        {
            int row = tid >> 2, k8 = (tid & 3) * 8;
            *reinterpret_cast<u32x4*>(&As[row * 40 + k8]) =
                *reinterpret_cast<const u32x4*>(&A[(size_t)row * lda + k0 + k8]);
        }
        if (BMODE == 0) {
            const u16* Bb = (const u16*)Bp;
            int row = tid >> 2, k8 = (tid & 3) * 8;
            *reinterpret_cast<u32x4*>(&Bs[row * 40 + k8]) =
                *reinterpret_cast<const u32x4*>(&Bb[(size_t)(n0 + row) * ldb + k0 + k8]);
        } else {
            const float* Bf = (const float*)Bp;
            int kk = tid >> 4, n4 = (tid & 15) * 4;
            f4 v0 = *reinterpret_cast<const f4*>(&Bf[(size_t)(k0 + kk) * ldb + n0 + n4]);
            f4 v1 = *reinterpret_cast<const f4*>(&Bf[(size_t)(k0 + kk + 16) * ldb + n0 + n4]);
#pragma unroll
            for (int i = 0; i < 4; i++) {
                Bs[(n4 + i) * 40 + kk] = f2bf(v0[i]);
                Bs[(n4 + i) * 40 + kk + 16] = f2bf(v1[i]);
            }
        }
        __syncthreads();
        bf16x8 bb = *reinterpret_cast<const bf16x8*>(&Bs[(w * 16 + l16) * 40 + quad * 8]);
#pragma unroll
        for (int mt = 0; mt < 4; mt++) {
            bf16x8 a = *reinterpret_cast<const bf16x8*>(&As[(mt * 16 + l16) * 40 + quad * 8]);
            acc[mt] = __builtin_amdgcn_mfma_f32_16x16x32_bf16(a, bb, acc[mt], 0, 0, 0);
        }
        __syncthreads();
    }
#pragma unroll
    for (int mt = 0; mt < 4; mt++)
#pragma unroll
        for (int i = 0; i < 4; i++) {
            int row = mt * 16 + quad * 4 + i;
            int col = n0 + w * 16 + l16;
            if (EPI == 0) {
                Cp[(size_t)blockIdx.y * 64 * Nout + (size_t)row * Nout + col] = acc[mt][i];
            } else {
                float ps = 0.f;
#pragma unroll
                for (int s = 0; s < 8; s++) ps += Pp[(size_t)s * 64 * Nout + (size_t)row * Nout + col];
                V[(size_t)row * Nout + col] = ps - acc[mt][i] - w2b2[col];
            }
        }
}

// ---------------------------------------------------------------------------
// gbat: split-K=4.  Gp[(ks*64+b)*1024 + r*32+c] partial of T_b wm_b^T.
// ---------------------------------------------------------------------------
__global__ __launch_bounds__(256) void gbat_kernel(
    const u16* __restrict__ T, const u16* __restrict__ wm, float* __restrict__ Gp)
{
    const int ks = blockIdx.x, b = blockIdx.y, tid = threadIdx.x;
    const int w = tid >> 6, lane = tid & 63, quad = lane >> 4, l16 = lane & 15;
    const int kb = ks * (H_ / 4);
    const u16* Ta = T + ((size_t)b * 32 + (w >> 1) * 16 + l16) * H_ + kb + quad * 8;
    const u16* Wb = wm + ((size_t)b * 32 + (w & 1) * 16 + l16) * H_ + kb + quad * 8;
    f32x4 acc = (f32x4){0.f, 0.f, 0.f, 0.f};
    for (int k = 0; k < H_ / 4; k += 32) {
        bf16x8 a  = *reinterpret_cast<const bf16x8*>(Ta + k);
        bf16x8 bb = *reinterpret_cast<const bf16x8*>(Wb + k);
        acc = __builtin_amdgcn_mfma_f32_16x16x32_bf16(a, bb, acc, 0, 0, 0);
    }
    const int row = (w >> 1) * 16 + quad * 4, col = (w & 1) * 16 + l16;
#pragma unroll
    for (int i = 0; i < 4; i++)
        Gp[((size_t)ks * 64 + b) * 1024 + (size_t)(row + i) * 32 + col] = acc[i];
}

// ---------------------------------------------------------------------------
__global__ __launch_bounds__(256) void zstar_kernel(
    const float* __restrict__ h1p, const float* __restrict__ encb1,
    const float* __restrict__ encW2, const float* __restrict__ encb2,
    const float* __restrict__ sigW, const float* __restrict__ sigb,
    float* __restrict__ zst, float* __restrict__ scal)
{
    const int b = blockIdx.x, tid = threadIdx.x;
    __shared__ float hs[H_];
    __shared__ float red[256];
    __shared__ float zsm[N_];
    for (int j = tid; j < H_; j += 256) {
        float s = encb1[j];
#pragma unroll
        for (int t = 0; t < 8; t++) s += h1p[(size_t)t * (64 * H_) + (size_t)b * H_ + j];
        hs[j] = s > 0.f ? s : 0.f;
    }
    __syncthreads();
    const int n = tid & 31, g = tid >> 5;
    float p = 0.f;
    for (int j = g; j < H_; j += 8) p += hs[j] * encW2[j * 32 + n];
    red[tid] = p;
    __syncthreads();
    if (tid < 32) {
        float s = encb2[tid];
#pragma unroll
        for (int t = 0; t < 8; t++) s += red[t * 32 + tid];
        zsm[tid] = s;
        zst[(size_t)b * N_ + tid] = s;
    }
    __syncthreads();
    if (tid == 0) {
        float zn = 0.f, a0 = sigb[0], a1 = sigb[1];
        for (int k = 0; k < N_; k++) {
            zn += zsm[k] * zsm[k];
            a0 += zsm[k] * sigW[k * 2 + 0];
            a1 += zsm[k] * sigW[k * 2 + 1];
        }
        scal[SC_SP * B_ + b] = expf(a0);
        scal[SC_SV * B_ + b] = expf(a1);
        scal[SC_ZN * B_ + b] = zn;
    }
}

// ---------------------------------------------------------------------------
// build_wm: grid (2 parts, B).  Each thread owns 4 consecutive j.
// ---------------------------------------------------------------------------
template <int HOUT>
__global__ __launch_bounds__(256) void build_wm_kernel(
    const float* __restrict__ z, const float* __restrict__ W1,
    const float* __restrict__ b1, u16* __restrict__ wm,
    u16* __restrict__ hb, float* __restrict__ hf)
{
    const int b = blockIdx.y;
    const int j = blockIdx.x * 1024 + threadIdx.x * 4;
    __shared__ float zs[N_];
    if (threadIdx.x < N_) zs[threadIdx.x] = z[(size_t)b * N_ + threadIdx.x];
    __syncthreads();
    f4 pre = *reinterpret_cast<const f4*>(&b1[j]);
#pragma unroll
    for (int k = 0; k < N_; k++) {
        f4 w = *reinterpret_cast<const f4*>(&W1[(size_t)k * H_ + j]);
        pre += zs[k] * w;
    }
    f4 m;
#pragma unroll
    for (int i = 0; i < 4; i++) m[i] = pre[i] > 0.f ? 1.f : 0.f;
    if (HOUT) {
        f4 h;
#pragma unroll
        for (int i = 0; i < 4; i++) h[i] = pre[i] > 0.f ? pre[i] : 0.f;
        *reinterpret_cast<f4*>(&hf[(size_t)b * H_ + j]) = h;
        u32x2 hp; hp[0] = pack2(h[0], h[1]); hp[1] = pack2(h[2], h[3]);
        *reinterpret_cast<u32x2*>(&hb[(size_t)b * H_ + j]) = hp;
    }
#pragma unroll 4
    for (int n = 0; n < N_; n++) {
        f4 w = *reinterpret_cast<const f4*>(&W1[(size_t)n * H_ + j]);
        u32x2 p; p[0] = pack2(w[0] * m[0], w[1] * m[1]); p[1] = pack2(w[2] * m[2], w[3] * m[3]);
        *reinterpret_cast<u32x2*>(&wm[((size_t)b * N_ + n) * H_ + j]) = p;
    }
}

// ---------------------------------------------------------------------------
// solve1: one wave per batch.  Register-resident Cholesky of Prec (lane i =
// row i), logdet, W=L^-1 (simultaneous forward solves), trace=||W||_F^2,
// dz = W^T eps, z_s, sp2/sv2.  All loops fully unrolled (compile-time lane
// indices for shuffles).
// ---------------------------------------------------------------------------
__global__ __launch_bounds__(64) void solve1_kernel(
    const float* __restrict__ Gp, const float* __restrict__ sigW,
    const float* __restrict__ sigb, const float* __restrict__ eps,
    const float* __restrict__ zst, float* __restrict__ zs2,
    float* __restrict__ scal)
{
    const int b = blockIdx.x;
    const int lane = threadIdx.x;
    const int i = lane & 31;
    const bool act = lane < 32;
    const float sp = scal[SC_SP * B_ + b];
    const float isp2 = 1.f / (sp * sp);
    const float w0 = act ? sigW[i * 2] : 0.f;
    const float w1 = act ? sigW[i * 2 + 1] : 0.f;

    float a[32];
#pragma unroll
    for (int j4 = 0; j4 < 8; j4++) {
        f4 g = (f4){0.f, 0.f, 0.f, 0.f};
#pragma unroll
        for (int ks = 0; ks < 4; ks++)
            g += *reinterpret_cast<const f4*>(&Gp[((size_t)ks * 64 + b) * 1024 + i * 32 + j4 * 4]);
#pragma unroll
        for (int q = 0; q < 4; q++) a[j4 * 4 + q] = g[q];
    }
#pragma unroll
    for (int j = 0; j < 32; j++) {
        float w0j = __shfl(w0, j, 64), w1j = __shfl(w1, j, 64);
        a[j] = a[j] * isp2 + 0.5f * (32.f * w0 * w0j + 12256.f * w1 * w1j) +
               ((i == j) ? 1.f : 0.f);
    }

    // Cholesky: lane i ends with a[k] = L_ik (k<=i)
    float ld = 0.f;
#pragma unroll
    for (int k = 0; k < 32; k++) {
        float lkk = sqrtf(__shfl(a[k], k, 64));
        ld += logf(lkk);
        float inv = 1.f / lkk;
        float lik = a[k] * inv;
        if (i == k) a[k] = lkk;
        else if (i > k) a[k] = lik;
#pragma unroll
        for (int j = k + 1; j < 32; j++) {
            float ljk = __shfl(a[k], j, 64);
            if (i > k) a[j] -= lik * ljk;
        }
    }

    // W = L^-1 (lower): lane i holds s[c] = W[i][c]
    float s[32];
#pragma unroll
    for (int c = 0; c < 32; c++) s[c] = (lane == c) ? 1.f : 0.f;
#pragma unroll
    for (int k = 0; k < 32; k++) {
        float inv = 1.f / __shfl(a[k], k, 64);
#pragma unroll
        for (int c = 0; c <= k; c++) {
            float wkc = __shfl(s[c], k, 64) * inv;
            if (i == k) s[c] = wkc;
            else if (i > k) s[c] -= a[k] * wkc;
        }
    }

    // trace(Prec^-1) = ||W||_F^2
    float tsl = 0.f;
    if (act) {
#pragma unroll
        for (int c = 0; c < 32; c++) tsl += s[c] * s[c];
    }
#pragma unroll
    for (int off = 32; off >= 1; off >>= 1) tsl += __shfl_xor(tsl, off, 64);

    // dz_j = sum_m W[m][j] * eps_m
    float em = act ? eps[(size_t)b * N_ + i] : 0.f;
    float dzl = 0.f;
#pragma unroll
    for (int j = 0; j < 32; j++) {
        float u = s[j] * em;
#pragma unroll
        for (int off = 32; off >= 1; off >>= 1) u += __shfl_xor(u, off, 64);
        if (lane == j) dzl = u;
    }
    float zsh = act ? (zst[(size_t)b * N_ + i] + dzl) : 0.f;
    if (act) zs2[(size_t)b * N_ + i] = zsh;

    float c0 = zsh * w0, c1 = zsh * w1;
#pragma unroll
    for (int off = 32; off >= 1; off >>= 1) {
        c0 += __shfl_xor(c0, off, 64);
        c1 += __shfl_xor(c1, off, 64);
    }
    if (lane == 0) {
        scal[SC_LD * B_ + b] = ld;
        scal[SC_TI * B_ + b] = 0.5f * tsl;   // fold the /2 here
        scal[SC_SP2 * B_ + b] = expf(sigb[0] + c0);
        scal[SC_SV2 * B_ + b] = expf(sigb[1] + c1);
    }
}

// ---------------------------------------------------------------------------
__global__ __launch_bounds__(256) void dsq_kernel(
    const float* __restrict__ x, const float* __restrict__ b2,
    const float* __restrict__ hf, const float* __restrict__ Pp,
    const float* __restrict__ V, const float* __restrict__ w2b2,
    float* __restrict__ scal)
{
    const int b = blockIdx.x, tid = threadIdx.x;
    __shared__ float red[256];
    float xn = 0.f, xb2 = 0.f, b2n = 0.f;
    for (int d = tid; d < D_; d += 256) {
        float xv = x[(size_t)b * D_ + d];
        float bv = b2[d];
        xn += xv * xv; xb2 += xv * bv; b2n += bv * bv;
    }
    float hP = 0.f, hV = 0.f, hW = 0.f;
    for (int j = tid; j < H_; j += 256) {
        float h = hf[(size_t)b * H_ + j];
        float ps = 0.f;
#pragma unroll
        for (int s = 0; s < 8; s++) ps += Pp[(size_t)s * (64 * H_) + (size_t)b * H_ + j];
        hP += h * ps;
        hV += h * V[(size_t)b * H_ + j];
        hW += h * w2b2[j];
    }
    float vals[6] = {xn, xb2, b2n, hP, hV, hW};
    float res[6];
    for (int q = 0; q < 6; q++) {
        red[tid] = vals[q]; __syncthreads();
        for (int off = 128; off > 0; off >>= 1) {
            if (tid < off) red[tid] += red[tid + off];
            __syncthreads();
        }
        res[q] = red[0]; __syncthreads();
    }
    if (tid == 0)
        scal[SC_DSQ * B_ + b] = res[0] - 2.f * res[1] - res[3] - res[4] + res[5] + res[2];
}

// ---------------------------------------------------------------------------
// tvec: t[b][n] = sum_j wm2[b][n][j] * V[b][j]  (wm2 already = W1*mask2 bf16)
// ---------------------------------------------------------------------------
__global__ __launch_bounds__(256) void tvec_kernel(
    const u16* __restrict__ wm, const float* __restrict__ V, float* __restrict__ t)
{
    const int b = blockIdx.x, tid = threadIdx.x;
    __shared__ float Vs[H_];
    for (int j = tid * 4; j < H_; j += 1024)
        *reinterpret_cast<f4*>(&Vs[j]) = *reinterpret_cast<const f4*>(&V[(size_t)b * H_ + j]);
    __syncthreads();
    const int w = tid >> 6, lane = tid & 63;
#pragma unroll
    for (int ni = 0; ni < 8; ni++) {
        int n = w * 8 + ni;
        const u16* row = wm + ((size_t)b * 32 + n) * H_;
        float s = 0.f;
#pragma unroll
        for (int it = 0; it < 8; it++) {
            int j = it * 256 + lane * 4;
            u32x2 p = *reinterpret_cast<const u32x2*>(&row[j]);
            f4 vv = *reinterpret_cast<const f4*>(&Vs[j]);
            s += bflo(p[0]) * vv[0] + bfhi(p[0]) * vv[1] +
                 bflo(p[1]) * vv[2] + bfhi(p[1]) * vv[3];
        }
#pragma unroll
        for (int off = 32; off >= 1; off >>= 1) s += __shfl_xor(s, off, 64);
        if (lane == 0) t[(size_t)b * N_ + n] = s;
    }
}

// ---------------------------------------------------------------------------
// solve2: one wave per batch.  Register Cholesky of G2; d_proj = ||L^-1 t||^2;
// assemble final output.
// ---------------------------------------------------------------------------
__global__ __launch_bounds__(64) void solve2_kernel(
    const float* __restrict__ G2p, const float* __restrict__ tv,
    const float* __restrict__ scal, float* __restrict__ out)
{
    const int b = blockIdx.x;
    const int lane = threadIdx.x;
    const int i = lane & 31;
    const bool act = lane < 32;

    float a[32];
#pragma unroll
    for (int j4 = 0; j4 < 8; j4++) {
        f4 g = (f4){0.f, 0.f, 0.f, 0.f};
#pragma unroll
        for (int ks = 0; ks < 4; ks++)
            g += *reinterpret_cast<const f4*>(&G2p[((size_t)ks * 64 + b) * 1024 + i * 32 + j4 * 4]);
#pragma unroll
        for (int q = 0; q < 4; q++) a[j4 * 4 + q] = g[q];
    }

#pragma unroll
    for (int k = 0; k < 32; k++) {
        float lkk = sqrtf(__shfl(a[k], k, 64));
        float inv = 1.f / lkk;
        float lik = a[k] * inv;
        if (i == k) a[k] = lkk;
        else if (i > k) a[k] = lik;
#pragma unroll
        for (int j = k + 1; j < 32; j++) {
            float ljk = __shfl(a[k], j, 64);
            if (i > k) a[j] -= lik * ljk;
        }
    }

    // forward solve L y = t ; d_proj = ||y||^2
    float r = act ? tv[(size_t)b * N_ + i] : 0.f;
#pragma unroll
    for (int k = 0; k < 32; k++) {
        float di = __shfl(a[k], k, 64);
        float yk = __shfl(r, k, 64) / di;
        if (i == k) r = yk;
        else if (i > k) r -= a[k] * yk;
    }
    float dp = act ? r * r : 0.f;
#pragma unroll
    for (int off = 32; off >= 1; off >>= 1) dp += __shfl_xor(dp, off, 64);

    if (lane == 0) {
        float sp2 = scal[SC_SP2 * B_ + b], sv2 = scal[SC_SV2 * B_ + b];
        float recon = scal[SC_DSQ * B_ + b] / (2.f * sv2 * sv2) +
                      dp * (0.5f / (sp2 * sp2) - 0.5f / (sv2 * sv2)) +
                      32.f * logf(sp2) + 12256.f * logf(sv2);
        float res = recon + 0.5f * scal[SC_ZN * B_ + b] + scal[SC_TI * B_ + b] +
                    scal[SC_LD * B_ + b];
        out[b] = res / (float)D_;
    }
}

// ---------------------------------------------------------------------------
extern "C" void kernel_launch(void* const* d_in, const int* in_sizes, int n_in,
                              void* d_out, int out_size, void* d_ws, size_t ws_size,
                              hipStream_t stream)
{
    const float* x     = (const float*)d_in[0];
    const float* eps   = (const float*)d_in[1];
    const float* encW1 = (const float*)d_in[2];
    const float* encb1 = (const float*)d_in[3];
    const float* encW2 = (const float*)d_in[4];
    const float* encb2 = (const float*)d_in[5];
    const float* decW1 = (const float*)d_in[6];
    const float* decb1 = (const float*)d_in[7];
    const float* decW2 = (const float*)d_in[8];
    const float* decb2 = (const float*)d_in[9];
    const float* sigW  = (const float*)d_in[10];
    const float* sigb  = (const float*)d_in[11];
    float* out = (float*)d_out;
    (void)in_sizes; (void)n_in; (void)out_size; (void)ws_size;

    float* ws = (float*)d_ws;
    size_t off = 0;
    auto allocf = [&](size_t nel) { float* p = ws + off; off += nel; return p; };
    auto allocb = [&](size_t nel) { u16* p = (u16*)(ws + off); off += nel / 2; return p; };

    u16*   w2b    = allocb((size_t)H_ * D_);
    u16*   Sb     = allocb((size_t)H_ * H_);
    u16*   wm     = allocb((size_t)B_ * N_ * H_);
    u16*   Tb     = allocb((size_t)B_ * N_ * H_);
    u16*   xb     = allocb((size_t)B_ * D_);
    u16*   h2b    = allocb((size_t)B_ * H_);
    float* h1p    = allocf((size_t)8 * B_ * H_);
    float* Pp     = allocf((size_t)8 * B_ * H_);
    float* h2f    = allocf((size_t)B_ * H_);
    float* V      = allocf((size_t)B_ * H_);
    float* w2b2   = allocf(H_);
    float* zst    = allocf((size_t)B_ * N_);
    float* zs2    = allocf((size_t)B_ * N_);
    float* tvbuf  = allocf((size_t)B_ * N_);
    float* Gp     = allocf((size_t)4 * B_ * N_ * N_);
    float* G2p    = allocf((size_t)4 * B_ * N_ * N_);
    float* scal   = allocf(8 * B_);
    float* slab   = allocf((size_t)136 * 8 * 16384);  // S slabs; reused for T slabs

    convW2_kernel<<<H_, 256, 0, stream>>>(decW2, decb2, w2b, w2b2);
    convX_kernel<<<(B_ * D_) / 1024, 256, 0, stream>>>(x, xb);
    // S = W2 W2^T, split-K=8
    mfmaS_kernel<<<dim3(8, 136), 256, 0, stream>>>(w2b, slab);
    reduceS_kernel<<<136, 256, 0, stream>>>(slab, Sb);
    // h1 partials = xb @ encW1 (split-K=8)
    skinny_kernel<1, 0><<<dim3(H_ / 64, 8), 256, 0, stream>>>(
        xb, D_, encW1, H_, D_ / 8, H_, h1p, nullptr, nullptr, nullptr);
    // P partials = xb @ w2b^T
    skinny_kernel<0, 0><<<dim3(H_ / 64, 8), 256, 0, stream>>>(
        xb, D_, w2b, D_, D_ / 8, H_, Pp, nullptr, nullptr, nullptr);
    zstar_kernel<<<B_, 256, 0, stream>>>(h1p, encb1, encW2, encb2, sigW, sigb, zst, scal);
    build_wm_kernel<0><<<dim3(2, B_), 256, 0, stream>>>(zst, decW1, decb1, wm, nullptr, nullptr);
    // T1 = wm1 @ S, split-K=2
    mfmaT_kernel<<<dim3(2, 256), 256, 0, stream>>>(wm, Sb, slab);
    reduceT_kernel<<<256, 256, 0, stream>>>(slab, Tb);
    gbat_kernel<<<dim3(4, B_), 256, 0, stream>>>(Tb, wm, Gp);
    solve1_kernel<<<B_, 64, 0, stream>>>(Gp, sigW, sigb, eps, zst, zs2, scal);
    build_wm_kernel<1><<<dim3(2, B_), 256, 0, stream>>>(zs2, decW1, decb1, wm, h2b, h2f);
    // T2 = wm2 @ S
    mfmaT_kernel<<<dim3(2, 256), 256, 0, stream>>>(wm, Sb, slab);
    reduceT_kernel<<<256, 256, 0, stream>>>(slab, Tb);
    gbat_kernel<<<dim3(4, B_), 256, 0, stream>>>(Tb, wm, G2p);
    // Q = h2 @ S ; V = Psum - Q - w2b2
    skinny_kernel<0, 1><<<dim3(H_ / 64, 1), 256, 0, stream>>>(
        h2b, H_, Sb, H_, H_, H_, nullptr, Pp, w2b2, V);
    dsq_kernel<<<B_, 256, 0, stream>>>(x, decb2, h2f, Pp, V, w2b2, scal);
    tvec_kernel<<<B_, 256, 0, stream>>>(wm, V, tvbuf);
    solve2_kernel<<<B_, 64, 0, stream>>>(G2p, tvbuf, scal, out);
}

// Round 5
// 600.134 us; speedup vs baseline: 8.1149x; 1.2768x over previous
//
#include <hip/hip_runtime.h>
#include <math.h>
#include <stdint.h>

constexpr int B_ = 64;
constexpr int D_ = 12288;
constexpr int N_ = 32;
constexpr int H_ = 2048;

#define SC_SP  0
#define SC_SV  1
#define SC_SP2 2
#define SC_SV2 3
#define SC_LD  4
#define SC_TI  5
#define SC_ZN  6

typedef unsigned short u16;
typedef __bf16 bf16x8 __attribute__((ext_vector_type(8)));
typedef float f32x4 __attribute__((ext_vector_type(4)));
typedef float f4 __attribute__((ext_vector_type(4)));
typedef unsigned int u32x4 __attribute__((ext_vector_type(4)));
typedef unsigned int u32x2 __attribute__((ext_vector_type(2)));

__device__ inline u16 f2bf(float f) {
    union { float f; uint32_t u; } v; v.f = f;
    uint32_t u = v.u;
    u += 0x7fffu + ((u >> 16) & 1u);   // round-to-nearest-even
    return (u16)(u >> 16);
}
__device__ inline uint32_t pack2(float a, float b) {
    return (uint32_t)f2bf(a) | ((uint32_t)f2bf(b) << 16);
}
__device__ inline float bflo(uint32_t p) { union {uint32_t u; float f;} c; c.u = p << 16; return c.f; }
__device__ inline float bfhi(uint32_t p) { union {uint32_t u; float f;} c; c.u = p & 0xffff0000u; return c.f; }
__device__ inline void tri_decode(int t, int& by, int& bx) {
    int rem = t; by = 0;
    while (rem >= 16 - by) { rem -= 16 - by; by++; }
    bx = by + rem;
}

// ---------------------------------------------------------------------------
// convW2: decW2 (H x D fp32) -> w2b (bf16), and w2b2[h] = sum_d W2[h,d]*b2[d]
// ---------------------------------------------------------------------------
__global__ __launch_bounds__(256) void convW2_kernel(
    const float* __restrict__ W2, const float* __restrict__ b2,
    u16* __restrict__ w2b, float* __restrict__ w2b2)
{
    const int h = blockIdx.x, tid = threadIdx.x;
    const float* src = W2 + (size_t)h * D_;
    u16* dst = w2b + (size_t)h * D_;
    float s = 0.f;
    for (int d = tid * 4; d < D_; d += 1024) {
        f4 v = *reinterpret_cast<const f4*>(&src[d]);
        f4 bv = *reinterpret_cast<const f4*>(&b2[d]);
        uint32_t p0 = pack2(v[0], v[1]);
        uint32_t p1 = pack2(v[2], v[3]);
        *reinterpret_cast<uint32_t*>(&dst[d]) = p0;
        *reinterpret_cast<uint32_t*>(&dst[d + 2]) = p1;
        s += v[0] * bv[0] + v[1] * bv[1] + v[2] * bv[2] + v[3] * bv[3];
    }
    __shared__ float red[256];
    red[tid] = s; __syncthreads();
    for (int off = 128; off > 0; off >>= 1) {
        if (tid < off) red[tid] += red[tid + off];
        __syncthreads();
    }
    if (tid == 0) w2b2[h] = red[0];
}

__global__ __launch_bounds__(256) void convX_kernel(
    const float* __restrict__ x, u16* __restrict__ xb)
{
    int i = (blockIdx.x * 256 + threadIdx.x) * 4;
    f4 v = *reinterpret_cast<const f4*>(&x[i]);
    *reinterpret_cast<uint32_t*>(&xb[i]) = pack2(v[0], v[1]);
    *reinterpret_cast<uint32_t*>(&xb[i + 2]) = pack2(v[2], v[3]);
}

// ---------------------------------------------------------------------------
// mfmaS: split-K S = W2 W2^T.  grid (8 ksplits, 136 upper tiles).
// ---------------------------------------------------------------------------
__global__ __launch_bounds__(256) void mfmaS_kernel(
    const u16* __restrict__ A, float* __restrict__ slab)
{
    const int ks = blockIdx.x;
    int by, bx; tri_decode(blockIdx.y, by, bx);
    const int m0 = by * 128, n0 = bx * 128, kb = ks * (D_ / 8);
    __shared__ u16 As[128 * 40];
    __shared__ u16 Bs[128 * 40];
    const int tid = threadIdx.x;
    const int w = tid >> 6, lane = tid & 63, quad = lane >> 4, l16 = lane & 15;
    const int moff = (w >> 1) * 64, noff = (w & 1) * 64;
    f32x4 acc[4][4];
#pragma unroll
    for (int i = 0; i < 4; i++)
#pragma unroll
        for (int j = 0; j < 4; j++) acc[i][j] = (f32x4){0.f, 0.f, 0.f, 0.f};

    for (int k0 = 0; k0 < D_ / 8; k0 += 32) {
#pragma unroll
        for (int it = 0; it < 2; it++) {
            int c = tid + it * 256;
            int row = c >> 2, k8 = (c & 3) * 8;
            *reinterpret_cast<u32x4*>(&As[row * 40 + k8]) =
                *reinterpret_cast<const u32x4*>(&A[(size_t)(m0 + row) * D_ + kb + k0 + k8]);
            *reinterpret_cast<u32x4*>(&Bs[row * 40 + k8]) =
                *reinterpret_cast<const u32x4*>(&A[(size_t)(n0 + row) * D_ + kb + k0 + k8]);
        }
        __syncthreads();
        bf16x8 a[4], bb[4];
#pragma unroll
        for (int t = 0; t < 4; t++) {
            a[t]  = *reinterpret_cast<const bf16x8*>(&As[(moff + t * 16 + l16) * 40 + quad * 8]);
            bb[t] = *reinterpret_cast<const bf16x8*>(&Bs[(noff + t * 16 + l16) * 40 + quad * 8]);
        }
#pragma unroll
        for (int mt = 0; mt < 4; mt++)
#pragma unroll
            for (int nt = 0; nt < 4; nt++)
                acc[mt][nt] = __builtin_amdgcn_mfma_f32_16x16x32_bf16(a[mt], bb[nt], acc[mt][nt], 0, 0, 0);
        __syncthreads();
    }
    float* out = slab + (((size_t)blockIdx.y * 8 + ks) << 14);
#pragma unroll
    for (int mt = 0; mt < 4; mt++)
#pragma unroll
        for (int nt = 0; nt < 4; nt++) {
            int r = moff + mt * 16 + quad * 4;
            int c = noff + nt * 16 + l16;
#pragma unroll
            for (int i = 0; i < 4; i++) out[(r + i) * 128 + c] = acc[mt][nt][i];
        }
}

// ---------------------------------------------------------------------------
// reduceS: sum 8 slabs -> bf16 S, mirrored via LDS transpose.
// ---------------------------------------------------------------------------
__global__ __launch_bounds__(256) void reduceS_kernel(
    const float* __restrict__ slab, u16* __restrict__ S)
{
    int by, bx; tri_decode(blockIdx.x, by, bx);
    const int i0 = by * 128, j0 = bx * 128;
    const int tid = threadIdx.x;
    __shared__ u16 tile[128][132];
    const float* base = slab + ((size_t)blockIdx.x * 8 << 14);
#pragma unroll
    for (int i = 0; i < 16; i++) {
        int e = i * 1024 + tid * 4;
        f4 s = (f4){0.f, 0.f, 0.f, 0.f};
#pragma unroll
        for (int ks = 0; ks < 8; ks++)
            s += *reinterpret_cast<const f4*>(&base[(size_t)ks * 16384 + e]);
        int r = e >> 7, c = e & 127;
        u32x2 p; p[0] = pack2(s[0], s[1]); p[1] = pack2(s[2], s[3]);
        *reinterpret_cast<u32x2*>(&S[(size_t)(i0 + r) * H_ + j0 + c]) = p;
        tile[r][c] = (u16)(p[0] & 0xffff); tile[r][c + 1] = (u16)(p[0] >> 16);
        tile[r][c + 2] = (u16)(p[1] & 0xffff); tile[r][c + 3] = (u16)(p[1] >> 16);
    }
    __syncthreads();
    if (by != bx) {
#pragma unroll
        for (int i = 0; i < 8; i++) {
            int idx = i * 256 + tid;
            int rr = idx >> 4, cc = (idx & 15) * 8;
            u32x4 v;
#pragma unroll
            for (int q = 0; q < 4; q++)
                v[q] = (uint32_t)tile[cc + 2 * q][rr] | ((uint32_t)tile[cc + 2 * q + 1][rr] << 16);
            *reinterpret_cast<u32x4*>(&S[(size_t)(j0 + rr) * H_ + i0 + cc]) = v;
        }
    }
}

// ---------------------------------------------------------------------------
// mfmaT: split-K=2 T = wm @ S^T (S sym).  grid (2, 256 tiles).
// ---------------------------------------------------------------------------
__global__ __launch_bounds__(256) void mfmaT_kernel(
    const u16* __restrict__ A, const u16* __restrict__ B, float* __restrict__ slab)
{
    const int ks = blockIdx.x;
    const int t = blockIdx.y;
    const int m0 = (t >> 4) * 128, n0 = (t & 15) * 128, kb = ks * (H_ / 2);
    __shared__ u16 As[128 * 40];
    __shared__ u16 Bs[128 * 40];
    const int tid = threadIdx.x;
    const int w = tid >> 6, lane = tid & 63, quad = lane >> 4, l16 = lane & 15;
    const int moff = (w >> 1) * 64, noff = (w & 1) * 64;
    f32x4 acc[4][4];
#pragma unroll
    for (int i = 0; i < 4; i++)
#pragma unroll
        for (int j = 0; j < 4; j++) acc[i][j] = (f32x4){0.f, 0.f, 0.f, 0.f};

    for (int k0 = 0; k0 < H_ / 2; k0 += 32) {
#pragma unroll
        for (int it = 0; it < 2; it++) {
            int c = tid + it * 256;
            int row = c >> 2, k8 = (c & 3) * 8;
            *reinterpret_cast<u32x4*>(&As[row * 40 + k8]) =
                *reinterpret_cast<const u32x4*>(&A[(size_t)(m0 + row) * H_ + kb + k0 + k8]);
            *reinterpret_cast<u32x4*>(&Bs[row * 40 + k8]) =
                *reinterpret_cast<const u32x4*>(&B[(size_t)(n0 + row) * H_ + kb + k0 + k8]);
        }
        __syncthreads();
        bf16x8 a[4], bb[4];
#pragma unroll
        for (int tt = 0; tt < 4; tt++) {
            a[tt]  = *reinterpret_cast<const bf16x8*>(&As[(moff + tt * 16 + l16) * 40 + quad * 8]);
            bb[tt] = *reinterpret_cast<const bf16x8*>(&Bs[(noff + tt * 16 + l16) * 40 + quad * 8]);
        }
#pragma unroll
        for (int mt = 0; mt < 4; mt++)
#pragma unroll
            for (int nt = 0; nt < 4; nt++)
                acc[mt][nt] = __builtin_amdgcn_mfma_f32_16x16x32_bf16(a[mt], bb[nt], acc[mt][nt], 0, 0, 0);
        __syncthreads();
    }
    float* out = slab + (((size_t)t * 2 + ks) << 14);
#pragma unroll
    for (int mt = 0; mt < 4; mt++)
#pragma unroll
        for (int nt = 0; nt < 4; nt++) {
            int r = moff + mt * 16 + quad * 4;
            int c = noff + nt * 16 + l16;
#pragma unroll
            for (int i = 0; i < 4; i++) out[(r + i) * 128 + c] = acc[mt][nt][i];
        }
}

__global__ __launch_bounds__(256) void reduceT_kernel(
    const float* __restrict__ slab, u16* __restrict__ T)
{
    const int t = blockIdx.x;
    const int m0 = (t >> 4) * 128, n0 = (t & 15) * 128;
    const int tid = threadIdx.x;
    const float* base = slab + ((size_t)t * 2 << 14);
#pragma unroll
    for (int i = 0; i < 16; i++) {
        int e = i * 1024 + tid * 4;
        f4 s = *reinterpret_cast<const f4*>(&base[e]) +
               *reinterpret_cast<const f4*>(&base[16384 + e]);
        int r = e >> 7, c = e & 127;
        u32x2 p; p[0] = pack2(s[0], s[1]); p[1] = pack2(s[2], s[3]);
        *reinterpret_cast<u32x2*>(&T[(size_t)(m0 + r) * H_ + n0 + c]) = p;
    }
}

// ---------------------------------------------------------------------------
// skinny64: C(64 x 2048) = A(64 x K bf16) * B^T, fp32 partial slab per ksplit.
// bmode 0: B bf16 row-major.  bmode 1: B fp32 K-major (transpose+cvt).
// ---------------------------------------------------------------------------
__device__ __forceinline__ void skinny_body(
    int n0, int ks, int bmode,
    const u16* __restrict__ A, int lda,
    const void* __restrict__ Bp, int ldb,
    int Kchunk, float* __restrict__ Cp)
{
    const int kbase = ks * Kchunk;
    __shared__ u16 As[64 * 40];
    __shared__ u16 Bs[64 * 40];
    const int tid = threadIdx.x;
    const int w = tid >> 6, lane = tid & 63, quad = lane >> 4, l16 = lane & 15;
    f32x4 acc[4];
#pragma unroll
    for (int t = 0; t < 4; t++) acc[t] = (f32x4){0.f, 0.f, 0.f, 0.f};

    for (int kt = 0; kt < Kchunk; kt += 32) {
        const int k0 = kbase + kt;
        {
            int row = tid >> 2, k8 = (tid & 3) * 8;
            *reinterpret_cast<u32x4*>(&As[row * 40 + k8]) =
                *reinterpret_cast<const u32x4*>(&A[(size_t)row * lda + k0 + k8]);
        }
        if (bmode == 0) {
            const u16* Bb = (const u16*)Bp;
            int row = tid >> 2, k8 = (tid & 3) * 8;
            *reinterpret_cast<u32x4*>(&Bs[row * 40 + k8]) =
                *reinterpret_cast<const u32x4*>(&Bb[(size_t)(n0 + row) * ldb + k0 + k8]);
        } else {
            const float* Bf = (const float*)Bp;
            int kk = tid >> 4, n4 = (tid & 15) * 4;
            f4 v0 = *reinterpret_cast<const f4*>(&Bf[(size_t)(k0 + kk) * ldb + n0 + n4]);
            f4 v1 = *reinterpret_cast<const f4*>(&Bf[(size_t)(k0 + kk + 16) * ldb + n0 + n4]);
#pragma unroll
            for (int i = 0; i < 4; i++) {
                Bs[(n4 + i) * 40 + kk] = f2bf(v0[i]);
                Bs[(n4 + i) * 40 + kk + 16] = f2bf(v1[i]);
            }
        }
        __syncthreads();
        bf16x8 bb = *reinterpret_cast<const bf16x8*>(&Bs[(w * 16 + l16) * 40 + quad * 8]);
#pragma unroll
        for (int mt = 0; mt < 4; mt++) {
            bf16x8 a = *reinterpret_cast<const bf16x8*>(&As[(mt * 16 + l16) * 40 + quad * 8]);
            acc[mt] = __builtin_amdgcn_mfma_f32_16x16x32_bf16(a, bb, acc[mt], 0, 0, 0);
        }
        __syncthreads();
    }
#pragma unroll
    for (int mt = 0; mt < 4; mt++)
#pragma unroll
        for (int i = 0; i < 4; i++) {
            int row = mt * 16 + quad * 4 + i;
            int col = n0 + w * 16 + l16;
            Cp[(size_t)ks * 64 * H_ + (size_t)row * H_ + col] = acc[mt][i];
        }
}

// merged launch: bx<32 -> P = xb @ w2b^T ; bx>=32 -> h1 = xb @ encW1
__global__ __launch_bounds__(256) void skinny_both_kernel(
    const u16* __restrict__ xb,
    const u16* __restrict__ w2b, const float* __restrict__ encW1,
    float* __restrict__ Pp, float* __restrict__ h1p)
{
    const int which = blockIdx.x >> 5;
    const int n0 = (blockIdx.x & 31) * 64;
    if (which == 0)
        skinny_body(n0, blockIdx.y, 0, xb, D_, w2b, D_, D_ / 8, Pp);
    else
        skinny_body(n0, blockIdx.y, 1, xb, D_, encW1, H_, D_ / 8, h1p);
}

// Q = h2 @ S, split-K=4
__global__ __launch_bounds__(256) void skinnyQ_kernel(
    const u16* __restrict__ h2b, const u16* __restrict__ Sb, float* __restrict__ Qp)
{
    skinny_body(blockIdx.x * 64, blockIdx.y, 0, h2b, H_, Sb, H_, H_ / 4, Qp);
}

// ---------------------------------------------------------------------------
// gbat: split-K=4.  Gp[(ks*64+b)*1024 + r*32+c] partial of T_b wm_b^T.
// ---------------------------------------------------------------------------
__global__ __launch_bounds__(256) void gbat_kernel(
    const u16* __restrict__ T, const u16* __restrict__ wm, float* __restrict__ Gp)
{
    const int ks = blockIdx.x, b = blockIdx.y, tid = threadIdx.x;
    const int w = tid >> 6, lane = tid & 63, quad = lane >> 4, l16 = lane & 15;
    const int kb = ks * (H_ / 4);
    const u16* Ta = T + ((size_t)b * 32 + (w >> 1) * 16 + l16) * H_ + kb + quad * 8;
    const u16* Wb = wm + ((size_t)b * 32 + (w & 1) * 16 + l16) * H_ + kb + quad * 8;
    f32x4 acc = (f32x4){0.f, 0.f, 0.f, 0.f};
    for (int k = 0; k < H_ / 4; k += 32) {
        bf16x8 a  = *reinterpret_cast<const bf16x8*>(Ta + k);
        bf16x8 bb = *reinterpret_cast<const bf16x8*>(Wb + k);
        acc = __builtin_amdgcn_mfma_f32_16x16x32_bf16(a, bb, acc, 0, 0, 0);
    }
    const int row = (w >> 1) * 16 + quad * 4, col = (w & 1) * 16 + l16;
#pragma unroll
    for (int i = 0; i < 4; i++)
        Gp[((size_t)ks * 64 + b) * 1024 + (size_t)(row + i) * 32 + col] = acc[i];
}

// ---------------------------------------------------------------------------
// reduce_h1: h1f = relu(sum of 8 slabs + encb1), flat over B*H.
// ---------------------------------------------------------------------------
__global__ __launch_bounds__(256) void reduce_h1_kernel(
    const float* __restrict__ h1p, const float* __restrict__ encb1,
    float* __restrict__ h1f)
{
    const int idx = (blockIdx.x * 256 + threadIdx.x) * 4;
    const int j = idx & (H_ - 1);
    f4 s = *reinterpret_cast<const f4*>(&encb1[j]);
#pragma unroll
    for (int t = 0; t < 8; t++)
        s += *reinterpret_cast<const f4*>(&h1p[(size_t)t * (B_ * H_) + idx]);
#pragma unroll
    for (int i = 0; i < 4; i++) s[i] = s[i] > 0.f ? s[i] : 0.f;
    *reinterpret_cast<f4*>(&h1f[idx]) = s;
}

// ---------------------------------------------------------------------------
// zpart: zp[ks][b][n] = sum_{j in chunk ks} h1f[b][j]*encW2[j][n]. grid (8,B).
// ---------------------------------------------------------------------------
__global__ __launch_bounds__(256) void zpart_kernel(
    const float* __restrict__ h1f, const float* __restrict__ encW2,
    float* __restrict__ zp)
{
    const int ks = blockIdx.x, b = blockIdx.y, tid = threadIdx.x;
    const int n = tid & 31, g = tid >> 5;
    const int jb = ks * 256 + g * 32;
    float p = 0.f;
#pragma unroll
    for (int jj = 0; jj < 32; jj++)
        p += h1f[(size_t)b * H_ + jb + jj] * encW2[(size_t)(jb + jj) * 32 + n];
    __shared__ float red[256];
    red[tid] = p; __syncthreads();
    if (tid < 32) {
        float s = 0.f;
#pragma unroll
        for (int t = 0; t < 8; t++) s += red[t * 32 + tid];
        zp[((size_t)ks * B_ + b) * 32 + tid] = s;
    }
}

// ---------------------------------------------------------------------------
// zfin: z = sum zp + encb2;  sp, sv, ||z||^2.  one wave per batch.
// ---------------------------------------------------------------------------
__global__ __launch_bounds__(64) void zfin_kernel(
    const float* __restrict__ zp, const float* __restrict__ encb2,
    const float* __restrict__ sigW, const float* __restrict__ sigb,
    float* __restrict__ zst, float* __restrict__ scal)
{
    const int b = blockIdx.x, lane = threadIdx.x;
    const bool act = lane < 32;
    float z = 0.f;
    if (act) {
        z = encb2[lane];
#pragma unroll
        for (int ks = 0; ks < 8; ks++) z += zp[((size_t)ks * B_ + b) * 32 + lane];
        zst[(size_t)b * N_ + lane] = z;
    }
    float w0 = act ? sigW[lane * 2] : 0.f;
    float w1 = act ? sigW[lane * 2 + 1] : 0.f;
    float zn = z * z, a0 = z * w0, a1 = z * w1;
#pragma unroll
    for (int off = 32; off >= 1; off >>= 1) {
        zn += __shfl_xor(zn, off, 64);
        a0 += __shfl_xor(a0, off, 64);
        a1 += __shfl_xor(a1, off, 64);
    }
    if (lane == 0) {
        scal[SC_SP * B_ + b] = expf(sigb[0] + a0);
        scal[SC_SV * B_ + b] = expf(sigb[1] + a1);
        scal[SC_ZN * B_ + b] = zn;
    }
}

// ---------------------------------------------------------------------------
// build_wm: grid (8 j-chunks, B), 64 threads; each thread 4 consecutive j.
// ---------------------------------------------------------------------------
template <int HOUT>
__global__ __launch_bounds__(64) void build_wm_kernel(
    const float* __restrict__ z, const float* __restrict__ W1,
    const float* __restrict__ b1, u16* __restrict__ wm,
    u16* __restrict__ hb, float* __restrict__ hf)
{
    const int b = blockIdx.y;
    const int j = blockIdx.x * 256 + threadIdx.x * 4;
    __shared__ float zs[N_];
    if (threadIdx.x < N_) zs[threadIdx.x] = z[(size_t)b * N_ + threadIdx.x];
    __syncthreads();
    f4 pre = *reinterpret_cast<const f4*>(&b1[j]);
#pragma unroll
    for (int k = 0; k < N_; k++) {
        f4 w = *reinterpret_cast<const f4*>(&W1[(size_t)k * H_ + j]);
        pre += zs[k] * w;
    }
    f4 m;
#pragma unroll
    for (int i = 0; i < 4; i++) m[i] = pre[i] > 0.f ? 1.f : 0.f;
    if (HOUT) {
        f4 h;
#pragma unroll
        for (int i = 0; i < 4; i++) h[i] = pre[i] > 0.f ? pre[i] : 0.f;
        *reinterpret_cast<f4*>(&hf[(size_t)b * H_ + j]) = h;
        u32x2 hp; hp[0] = pack2(h[0], h[1]); hp[1] = pack2(h[2], h[3]);
        *reinterpret_cast<u32x2*>(&hb[(size_t)b * H_ + j]) = hp;
    }
#pragma unroll 4
    for (int n = 0; n < N_; n++) {
        f4 w = *reinterpret_cast<const f4*>(&W1[(size_t)n * H_ + j]);
        u32x2 p; p[0] = pack2(w[0] * m[0], w[1] * m[1]); p[1] = pack2(w[2] * m[2], w[3] * m[3]);
        *reinterpret_cast<u32x2*>(&wm[((size_t)b * N_ + n) * H_ + j]) = p;
    }
}

// ---------------------------------------------------------------------------
// solve1: register-resident Cholesky etc (one wave per batch).
// ---------------------------------------------------------------------------
__global__ __launch_bounds__(64) void solve1_kernel(
    const float* __restrict__ Gp, const float* __restrict__ sigW,
    const float* __restrict__ sigb, const float* __restrict__ eps,
    const float* __restrict__ zst, float* __restrict__ zs2,
    float* __restrict__ scal)
{
    const int b = blockIdx.x;
    const int lane = threadIdx.x;
    const int i = lane & 31;
    const bool act = lane < 32;
    const float sp = scal[SC_SP * B_ + b];
    const float isp2 = 1.f / (sp * sp);
    const float w0 = act ? sigW[i * 2] : 0.f;
    const float w1 = act ? sigW[i * 2 + 1] : 0.f;

    float a[32];
#pragma unroll
    for (int j4 = 0; j4 < 8; j4++) {
        f4 g = (f4){0.f, 0.f, 0.f, 0.f};
#pragma unroll
        for (int ks = 0; ks < 4; ks++)
            g += *reinterpret_cast<const f4*>(&Gp[((size_t)ks * 64 + b) * 1024 + i * 32 + j4 * 4]);
#pragma unroll
        for (int q = 0; q < 4; q++) a[j4 * 4 + q] = g[q];
    }
#pragma unroll
    for (int j = 0; j < 32; j++) {
        float w0j = __shfl(w0, j, 64), w1j = __shfl(w1, j, 64);
        a[j] = a[j] * isp2 + 0.5f * (32.f * w0 * w0j + 12256.f * w1 * w1j) +
               ((i == j) ? 1.f : 0.f);
    }

    float ld = 0.f;
#pragma unroll
    for (int k = 0; k < 32; k++) {
        float lkk = sqrtf(__shfl(a[k], k, 64));
        ld += logf(lkk);
        float inv = 1.f / lkk;
        float lik = a[k] * inv;
        if (i == k) a[k] = lkk;
        else if (i > k) a[k] = lik;
#pragma unroll
        for (int j = k + 1; j < 32; j++) {
            float ljk = __shfl(a[k], j, 64);
            if (i > k) a[j] -= lik * ljk;
        }
    }

    float s[32];
#pragma unroll
    for (int c = 0; c < 32; c++) s[c] = (lane == c) ? 1.f : 0.f;
#pragma unroll
    for (int k = 0; k < 32; k++) {
        float inv = 1.f / __shfl(a[k], k, 64);
#pragma unroll
        for (int c = 0; c <= k; c++) {
            float wkc = __shfl(s[c], k, 64) * inv;
            if (i == k) s[c] = wkc;
            else if (i > k) s[c] -= a[k] * wkc;
        }
    }

    float tsl = 0.f;
    if (act) {
#pragma unroll
        for (int c = 0; c < 32; c++) tsl += s[c] * s[c];
    }
#pragma unroll
    for (int off = 32; off >= 1; off >>= 1) tsl += __shfl_xor(tsl, off, 64);

    float em = act ? eps[(size_t)b * N_ + i] : 0.f;
    float dzl = 0.f;
#pragma unroll
    for (int j = 0; j < 32; j++) {
        float u = s[j] * em;
#pragma unroll
        for (int off = 32; off >= 1; off >>= 1) u += __shfl_xor(u, off, 64);
        if (lane == j) dzl = u;
    }
    float zsh = act ? (zst[(size_t)b * N_ + i] + dzl) : 0.f;
    if (act) zs2[(size_t)b * N_ + i] = zsh;

    float c0 = zsh * w0, c1 = zsh * w1;
#pragma unroll
    for (int off = 32; off >= 1; off >>= 1) {
        c0 += __shfl_xor(c0, off, 64);
        c1 += __shfl_xor(c1, off, 64);
    }
    if (lane == 0) {
        scal[SC_LD * B_ + b] = ld;
        scal[SC_TI * B_ + b] = 0.5f * tsl;
        scal[SC_SP2 * B_ + b] = expf(sigb[0] + c0);
        scal[SC_SV2 * B_ + b] = expf(sigb[1] + c1);
    }
}

// ---------------------------------------------------------------------------
// vbuild: V = sum(Pp,8) - sum(Qp,4) - w2b2, flat over B*H.
// ---------------------------------------------------------------------------
__global__ __launch_bounds__(256) void vbuild_kernel(
    const float* __restrict__ Pp, const float* __restrict__ Qp,
    const float* __restrict__ w2b2, float* __restrict__ V)
{
    const int idx = (blockIdx.x * 256 + threadIdx.x) * 4;
    const int j = idx & (H_ - 1);
    f4 s = (f4){0.f, 0.f, 0.f, 0.f};
#pragma unroll
    for (int t = 0; t < 8; t++)
        s += *reinterpret_cast<const f4*>(&Pp[(size_t)t * (B_ * H_) + idx]);
#pragma unroll
    for (int t = 0; t < 4; t++)
        s -= *reinterpret_cast<const f4*>(&Qp[(size_t)t * (B_ * H_) + idx]);
    s -= *reinterpret_cast<const f4*>(&w2b2[j]);
    *reinterpret_cast<f4*>(&V[idx]) = s;
}

// ---------------------------------------------------------------------------
// dsq_part: grid (B, 8).  6 partial sums per (b,ks) -> dsqp[b*48 + ks*6 + q].
// q order: {xn, xb2, b2n, hP, hV, hW}
// ---------------------------------------------------------------------------
__global__ __launch_bounds__(256) void dsq_part_kernel(
    const float* __restrict__ x, const float* __restrict__ b2,
    const float* __restrict__ hf, const float* __restrict__ Pp,
    const float* __restrict__ V, const float* __restrict__ w2b2,
    float* __restrict__ dsqp)
{
    const int b = blockIdx.x, ks = blockIdx.y, tid = threadIdx.x;
    float xn = 0.f, xb2 = 0.f, b2n = 0.f;
    const int dbase = ks * (D_ / 8);
    for (int d = dbase + tid; d < dbase + D_ / 8; d += 256) {
        float xv = x[(size_t)b * D_ + d];
        float bv = b2[d];
        xn += xv * xv; xb2 += xv * bv; b2n += bv * bv;
    }
    float hP = 0.f, hV = 0.f, hW = 0.f;
    {
        int j = ks * (H_ / 8) + tid;
        float h = hf[(size_t)b * H_ + j];
        float ps = 0.f;
#pragma unroll
        for (int s = 0; s < 8; s++) ps += Pp[(size_t)s * (B_ * H_) + (size_t)b * H_ + j];
        hP = h * ps;
        hV = h * V[(size_t)b * H_ + j];
        hW = h * w2b2[j];
    }
    __shared__ float red[256];
    float vals[6] = {xn, xb2, b2n, hP, hV, hW};
#pragma unroll
    for (int q = 0; q < 6; q++) {
        red[tid] = vals[q]; __syncthreads();
        for (int off = 128; off > 0; off >>= 1) {
            if (tid < off) red[tid] += red[tid + off];
            __syncthreads();
        }
        if (tid == 0) dsqp[b * 48 + ks * 6 + q] = red[0];
        __syncthreads();
    }
}

// ---------------------------------------------------------------------------
// tvec_part: tp[ks][b][n] = sum_{j chunk} wm2[b][n][j]*V[b][j].  grid (B,4).
// ---------------------------------------------------------------------------
__global__ __launch_bounds__(256) void tvec_part_kernel(
    const u16* __restrict__ wm, const float* __restrict__ V, float* __restrict__ tp)
{
    const int b = blockIdx.x, ks = blockIdx.y, tid = threadIdx.x;
    const int jb = ks * (H_ / 4);
    __shared__ float Vs[H_ / 4];
    for (int j = tid * 4; j < H_ / 4; j += 1024)
        *reinterpret_cast<f4*>(&Vs[j]) = *reinterpret_cast<const f4*>(&V[(size_t)b * H_ + jb + j]);
    __syncthreads();
    const int w = tid >> 6, lane = tid & 63;
#pragma unroll
    for (int ni = 0; ni < 8; ni++) {
        int n = w * 8 + ni;
        const u16* row = wm + ((size_t)b * 32 + n) * H_ + jb;
        float s = 0.f;
#pragma unroll
        for (int it = 0; it < 2; it++) {
            int j = it * 256 + lane * 4;
            u32x2 p = *reinterpret_cast<const u32x2*>(&row[j]);
            f4 vv = *reinterpret_cast<const f4*>(&Vs[j]);
            s += bflo(p[0]) * vv[0] + bfhi(p[0]) * vv[1] +
                 bflo(p[1]) * vv[2] + bfhi(p[1]) * vv[3];
        }
#pragma unroll
        for (int off = 32; off >= 1; off >>= 1) s += __shfl_xor(s, off, 64);
        if (lane == 0) tp[((size_t)ks * B_ + b) * 32 + n] = s;
    }
}

// ---------------------------------------------------------------------------
// solve2: register Cholesky of G2; d_proj = ||L^-1 t||^2; fold dsq finalize;
// assemble output.  one wave per batch.
// ---------------------------------------------------------------------------
__global__ __launch_bounds__(64) void solve2_kernel(
    const float* __restrict__ G2p, const float* __restrict__ tp,
    const float* __restrict__ dsqp, const float* __restrict__ scal,
    float* __restrict__ out)
{
    const int b = blockIdx.x;
    const int lane = threadIdx.x;
    const int i = lane & 31;
    const bool act = lane < 32;

    // dsq = sum over 48 partials with signs {+1,-2,+1,-1,-1,+1}
    float dv = 0.f;
    if (lane < 48) {
        const float sgn[6] = {1.f, -2.f, 1.f, -1.f, -1.f, 1.f};
        dv = dsqp[b * 48 + lane] * sgn[lane % 6];
    }
#pragma unroll
    for (int off = 32; off >= 1; off >>= 1) dv += __shfl_xor(dv, off, 64);
    const float dsq = dv;

    float a[32];
#pragma unroll
    for (int j4 = 0; j4 < 8; j4++) {
        f4 g = (f4){0.f, 0.f, 0.f, 0.f};
#pragma unroll
        for (int ks = 0; ks < 4; ks++)
            g += *reinterpret_cast<const f4*>(&G2p[((size_t)ks * 64 + b) * 1024 + i * 32 + j4 * 4]);
#pragma unroll
        for (int q = 0; q < 4; q++) a[j4 * 4 + q] = g[q];
    }

#pragma unroll
    for (int k = 0; k < 32; k++) {
        float lkk = sqrtf(__shfl(a[k], k, 64));
        float inv = 1.f / lkk;
        float lik = a[k] * inv;
        if (i == k) a[k] = lkk;
        else if (i > k) a[k] = lik;
#pragma unroll
        for (int j = k + 1; j < 32; j++) {
            float ljk = __shfl(a[k], j, 64);
            if (i > k) a[j] -= lik * ljk;
        }
    }

    float r = 0.f;
    if (act) {
#pragma unroll
        for (int ks = 0; ks < 4; ks++) r += tp[((size_t)ks * B_ + b) * 32 + i];
    }
#pragma unroll
    for (int k = 0; k < 32; k++) {
        float di = __shfl(a[k], k, 64);
        float yk = __shfl(r, k, 64) / di;
        if (i == k) r = yk;
        else if (i > k) r -= a[k] * yk;
    }
    float dp = act ? r * r : 0.f;
#pragma unroll
    for (int off = 32; off >= 1; off >>= 1) dp += __shfl_xor(dp, off, 64);

    if (lane == 0) {
        float sp2 = scal[SC_SP2 * B_ + b], sv2 = scal[SC_SV2 * B_ + b];
        float recon = dsq / (2.f * sv2 * sv2) +
                      dp * (0.5f / (sp2 * sp2) - 0.5f / (sv2 * sv2)) +
                      32.f * logf(sp2) + 12256.f * logf(sv2);
        float res = recon + 0.5f * scal[SC_ZN * B_ + b] + scal[SC_TI * B_ + b] +
                    scal[SC_LD * B_ + b];
        out[b] = res / (float)D_;
    }
}

// ---------------------------------------------------------------------------
extern "C" void kernel_launch(void* const* d_in, const int* in_sizes, int n_in,
                              void* d_out, int out_size, void* d_ws, size_t ws_size,
                              hipStream_t stream)
{
    const float* x     = (const float*)d_in[0];
    const float* eps   = (const float*)d_in[1];
    const float* encW1 = (const float*)d_in[2];
    const float* encb1 = (const float*)d_in[3];
    const float* encW2 = (const float*)d_in[4];
    const float* encb2 = (const float*)d_in[5];
    const float* decW1 = (const float*)d_in[6];
    const float* decb1 = (const float*)d_in[7];
    const float* decW2 = (const float*)d_in[8];
    const float* decb2 = (const float*)d_in[9];
    const float* sigW  = (const float*)d_in[10];
    const float* sigb  = (const float*)d_in[11];
    float* out = (float*)d_out;
    (void)in_sizes; (void)n_in; (void)out_size; (void)ws_size;

    float* ws = (float*)d_ws;
    size_t off = 0;
    auto allocf = [&](size_t nel) { float* p = ws + off; off += nel; return p; };
    auto allocb = [&](size_t nel) { u16* p = (u16*)(ws + off); off += nel / 2; return p; };

    u16*   w2b    = allocb((size_t)H_ * D_);
    u16*   Sb     = allocb((size_t)H_ * H_);
    u16*   wm     = allocb((size_t)B_ * N_ * H_);
    u16*   Tb     = allocb((size_t)B_ * N_ * H_);
    u16*   xb     = allocb((size_t)B_ * D_);
    u16*   h2b    = allocb((size_t)B_ * H_);
    float* h1p    = allocf((size_t)8 * B_ * H_);
    float* Pp     = allocf((size_t)8 * B_ * H_);
    float* Qp     = allocf((size_t)4 * B_ * H_);
    float* h1f    = allocf((size_t)B_ * H_);
    float* h2f    = allocf((size_t)B_ * H_);
    float* V      = allocf((size_t)B_ * H_);
    float* w2b2   = allocf(H_);
    float* zst    = allocf((size_t)B_ * N_);
    float* zs2    = allocf((size_t)B_ * N_);
    float* zp     = allocf((size_t)8 * B_ * N_);
    float* tp     = allocf((size_t)4 * B_ * N_);
    float* dsqp   = allocf((size_t)B_ * 48);
    float* Gp     = allocf((size_t)4 * B_ * N_ * N_);
    float* G2p    = allocf((size_t)4 * B_ * N_ * N_);
    float* scal   = allocf(8 * B_);
    float* slab   = allocf((size_t)136 * 8 * 16384);  // S slabs; reused for T slabs

    convW2_kernel<<<H_, 256, 0, stream>>>(decW2, decb2, w2b, w2b2);
    convX_kernel<<<(B_ * D_) / 1024, 256, 0, stream>>>(x, xb);
    // S = W2 W2^T, split-K=8
    mfmaS_kernel<<<dim3(8, 136), 256, 0, stream>>>(w2b, slab);
    reduceS_kernel<<<136, 256, 0, stream>>>(slab, Sb);
    // h1 & P partials (merged, split-K=8)
    skinny_both_kernel<<<dim3(64, 8), 256, 0, stream>>>(xb, w2b, encW1, Pp, h1p);
    reduce_h1_kernel<<<(B_ * H_) / 1024, 256, 0, stream>>>(h1p, encb1, h1f);
    zpart_kernel<<<dim3(8, B_), 256, 0, stream>>>(h1f, encW2, zp);
    zfin_kernel<<<B_, 64, 0, stream>>>(zp, encb2, sigW, sigb, zst, scal);
    build_wm_kernel<0><<<dim3(8, B_), 64, 0, stream>>>(zst, decW1, decb1, wm, nullptr, nullptr);
    // T1 = wm1 @ S, split-K=2
    mfmaT_kernel<<<dim3(2, 256), 256, 0, stream>>>(wm, Sb, slab);
    reduceT_kernel<<<256, 256, 0, stream>>>(slab, Tb);
    gbat_kernel<<<dim3(4, B_), 256, 0, stream>>>(Tb, wm, Gp);
    solve1_kernel<<<B_, 64, 0, stream>>>(Gp, sigW, sigb, eps, zst, zs2, scal);
    build_wm_kernel<1><<<dim3(8, B_), 64, 0, stream>>>(zs2, decW1, decb1, wm, h2b, h2f);
    // T2 = wm2 @ S
    mfmaT_kernel<<<dim3(2, 256), 256, 0, stream>>>(wm, Sb, slab);
    reduceT_kernel<<<256, 256, 0, stream>>>(slab, Tb);
    gbat_kernel<<<dim3(4, B_), 256, 0, stream>>>(Tb, wm, G2p);
    // Q = h2 @ S (split-K=4); V = sum(Pp) - sum(Qp) - w2b2
    skinnyQ_kernel<<<dim3(32, 4), 256, 0, stream>>>(h2b, Sb, Qp);
    vbuild_kernel<<<(B_ * H_) / 1024, 256, 0, stream>>>(Pp, Qp, w2b2, V);
    dsq_part_kernel<<<dim3(B_, 8), 256, 0, stream>>>(x, decb2, h2f, Pp, V, w2b2, dsqp);
    tvec_part_kernel<<<dim3(B_, 4), 256, 0, stream>>>(wm, V, tp);
    solve2_kernel<<<B_, 64, 0, stream>>>(G2p, tp, dsqp, scal, out);
}